// Round 17
// baseline (984.787 us; speedup 1.0000x reference)
//
#include <hip/hip_runtime.h>
#include <math.h>

#define N_NODES 20000
#define N_EDGES 320000
#define NCHUNK (N_EDGES / 32)      // 10000
#define CH_STRIDE 1536             // 48 p-rows * 32 edges (ush) per chunk
#define DIM 64
#define SUB 16
#define NRBF 8
#define NB 5
#define LAYERS 3
#define FCIN (NRBF*SUB*NB + SUB)   // 656
#define KPAD 672
#define NKK 21
#define HD 64
#define CUTOFF 5.0f
#define TS 680                     // LDS cat-tile row stride (ush): 2-way banks
#define GRID 1024                  // 4 blocks/CU guaranteed co-resident
#define NTILES (N_NODES / 16)      // 1250

typedef __attribute__((ext_vector_type(8))) short short8;
typedef __attribute__((ext_vector_type(4))) float float4v;

__device__ __forceinline__ float ssp(float x) {
    float sp = fmaxf(x, 0.0f) + log1pf(expf(-fabsf(x)));
    return sp - 0.69314718055994530942f;
}

__device__ __forceinline__ unsigned short f2bf(float x) {
    unsigned int u = __float_as_uint(x);
    unsigned int r = (u + 0x7FFFu + ((u >> 16) & 1u)) >> 16;
    return (unsigned short)r;
}

// Device-scope grid barrier (persistent-kernel pattern). Counter zeroed by a
// hipMemsetAsync node before each launch; monotonic single-use per counter.
__device__ __forceinline__ void grid_barrier(int* bar) {
    __syncthreads();
    if (threadIdx.x == 0) {
        __threadfence();
        __hip_atomic_fetch_add(bar, 1, __ATOMIC_ACQ_REL, __HIP_MEMORY_SCOPE_AGENT);
        while (__hip_atomic_load(bar, __ATOMIC_ACQUIRE, __HIP_MEMORY_SCOPE_AGENT) < GRID)
            __builtin_amdgcn_s_sleep(2);
    }
    __syncthreads();
}

__global__ __launch_bounds__(256, 4) void k_mega(
    const int* __restrict__ species, const int* __restrict__ esrc,
    const int* __restrict__ edst, const float* __restrict__ dist,
    const float* __restrict__ sw, const float* __restrict__ bo,
    const float* __restrict__ Wsp, const float* __restrict__ Wsm,
    const float* __restrict__ bsm,
    const float* __restrict__ w0, const float* __restrict__ b0,
    const float* __restrict__ w1, const float* __restrict__ b1,
    const float* __restrict__ w2, const float* __restrict__ b2,
    float* __restrict__ xi,
    unsigned short* __restrict__ uTi,
    unsigned short* __restrict__ mi0, unsigned short* __restrict__ mi1,
    unsigned short* __restrict__ si16,
    short* __restrict__ w0f, short* __restrict__ w1f, short* __restrict__ w2f,
    short* __restrict__ wsmf, int* __restrict__ rowptr, int* __restrict__ bars)
{
    __shared__ __align__(16) unsigned short tile[16][TS];    // 21760 B
    __shared__ float xs[8][64];                              // 2048 B (setup)
    unsigned short (*h1)[72] = (unsigned short (*)[72])((char*)tile);
    unsigned short (*h2)[72] = (unsigned short (*)[72])((char*)tile + 4608);
    float (*xi_s)[68]        = (float (*)[68])((char*)tile + 9216);

    const int tid = threadIdx.x;
    const int gid = blockIdx.x * 256 + tid;

    // ================= setup (partitioned across the grid) =================
    if (gid <= N_NODES) {                       // rowptr
        int a = 0, b = N_EDGES;
        while (a < b) { int m = (a + b) >> 1; if (esrc[m] < gid) a = m + 1; else b = m; }
        rowptr[gid] = a;
    }
    {                                           // pack w0/w1/w2
        const int SZ0 = LAYERS * NKK * 4 * 64 * 8;
        const int SZ12 = LAYERS * 2 * 4 * 64 * 8;
        int i = gid;
        if (i < SZ0) {
            int j = i & 7, t = i >> 3;
            int lane = t & 63; t >>= 6;
            int nf = t & 3; t >>= 2;
            int kk = t % NKK, l = t / NKK;
            int kp = kk * 32 + (lane >> 4) * 8 + j;
            int col = nf * 16 + (lane & 15);
            float v = 0.0f;
            if (kp < FCIN) {
                int orig;
                if (kp < 640) {
                    int j10 = kp >> 6, rem = kp & 63, g = rem >> 4, s = rem & 15;
                    int p = g + 4 * j10;
                    orig = (p / 5) * 80 + s * 5 + (p - 5 * (p / 5));
                } else orig = kp;
                v = w0[((size_t)l * FCIN + orig) * HD + col];
            }
            w0f[i] = (short)f2bf(v);
        } else if (i - SZ0 < 2 * SZ12) {
            i -= SZ0;
            const float* W = (i < SZ12) ? w1 : w2;
            short* Wf = (i < SZ12) ? w1f : w2f;
            int ii = (i < SZ12) ? i : i - SZ12;
            int j = ii & 7, t = ii >> 3;
            int lane = t & 63; t >>= 6;
            int nf = t & 3; t >>= 2;
            int kk = t & 1, l = t >> 1;
            int kp = kk * 32 + (lane >> 4) * 8 + j;
            int col = nf * 16 + (lane & 15);
            Wf[ii] = (short)f2bf(W[((size_t)l * HD + kp) * HD + col]);
        }
    }
    if (gid < LAYERS * 2 * 2 * 512) {           // pack Wsm for h-GEMM
        int i = gid;
        int j = i & 7, t = i >> 3;
        int lane = t & 63; t >>= 6;
        int nf = t & 1; t >>= 1;
        int kk = t & 1, l = t >> 1;
        int kp = kk * 32 + (lane >> 4) * 8 + j;
        int col = nf * 16 + (lane & 15);
        wsmf[i] = (short)f2bf(Wsm[(size_t)l * DIM * 2 * SUB + kp * 2 * SUB + col]);
    }
    for (int e = gid; e < N_EDGES; e += GRID * 256) {   // uTi (chunk-tiled)
        float d = dist[e];
        float s = sw[e];
        float rbv[NRBF], bov[NB];
        #pragma unroll
        for (int r = 0; r < NRBF; ++r) {
            float mu = (CUTOFF / (NRBF - 1)) * (float)r;
            float z = (d - mu) * ((float)NRBF / CUTOFF);
            rbv[r] = s * expf(-0.5f * z * z);
        }
        #pragma unroll
        for (int b = 0; b < NB; ++b) bov[b] = bo[e * NB + b];
        unsigned short* out = uTi + (size_t)(e >> 5) * CH_STRIDE + (e & 31);
        #pragma unroll
        for (int p = 0; p < 48; ++p) {
            float v = (p < 40) ? rbv[p / 5] * bov[p % 5] : 0.0f;
            out[p * 32] = f2bf(v);
        }
    }
    for (int nb = blockIdx.x; nb < N_NODES / 8; nb += GRID) {   // init xi + h(0)
        const int nl = tid >> 5, j = tid & 31;
        const int n = nb * 8 + nl;
        const int sp = species[n];
        float v0 = Wsp[sp * DIM + j];
        float v1 = Wsp[sp * DIM + 32 + j];
        xi[(size_t)n * DIM + j] = v0;
        xi[(size_t)n * DIM + 32 + j] = v1;
        xs[nl][j] = v0;
        xs[nl][32 + j] = v1;
        __syncthreads();
        float v = bsm[j];
        const float* xr = &xs[nl][0];
        #pragma unroll 8
        for (int d = 0; d < DIM; ++d) v = fmaf(xr[d], Wsm[d * 2 * SUB + j], v);
        if (j < SUB) si16[(size_t)n * SUB + j] = f2bf(v);
        else         mi0[(size_t)n * SUB + (j - SUB)] = f2bf(v);
        __syncthreads();
    }
    grid_barrier(&bars[0]);

    // ================= layers =================
    const int lane = tid & 63;
    const int w = tid >> 6;
    const int x = lane & 15, g = lane >> 4;

    for (int l = 0; l < LAYERS; ++l) {
        const unsigned short* mi_rd = (l & 1) ? mi1 : mi0;
        unsigned short* mi_wr = (l & 1) ? mi0 : mi1;

        for (int t = blockIdx.x; t < NTILES; t += GRID) {
            const int n0 = t * 16;

            // ---- Phase A: union-sweep MFMA aggregation into LDS tile ----
            const unsigned short* mx = mi_rd + x;
            const int base = n0 + 4 * w;
            int rp[5];
            #pragma unroll
            for (int i = 0; i < 5; ++i) rp[i] = rowptr[base + i];

            float4v a00={0,0,0,0}, a01={0,0,0,0}, a02={0,0,0,0};
            float4v a10={0,0,0,0}, a11={0,0,0,0}, a12={0,0,0,0};
            float4v a20={0,0,0,0}, a21={0,0,0,0}, a22={0,0,0,0};
            float4v a30={0,0,0,0}, a31={0,0,0,0}, a32={0,0,0,0};

            const int kb = g * 8;
            for (int ba = rp[0] & ~31; ba < rp[4]; ba += 32) {
                int4 i0 = *(const int4*)(edst + ba + kb);
                int4 i1 = *(const int4*)(edst + ba + kb + 4);
                short8 braw;
                braw[0] = (short)mx[(size_t)i0.x * 16];
                braw[1] = (short)mx[(size_t)i0.y * 16];
                braw[2] = (short)mx[(size_t)i0.z * 16];
                braw[3] = (short)mx[(size_t)i0.w * 16];
                braw[4] = (short)mx[(size_t)i1.x * 16];
                braw[5] = (short)mx[(size_t)i1.y * 16];
                braw[6] = (short)mx[(size_t)i1.z * 16];
                braw[7] = (short)mx[(size_t)i1.w * 16];

                const unsigned short* ap = uTi + (size_t)(ba >> 5) * CH_STRIDE + x * 32 + kb;
                short8 f0 = *(const short8*)(ap);
                short8 f1 = *(const short8*)(ap + 512);
                short8 f2 = *(const short8*)(ap + 1024);

                #define NODE_STEP(ND, A0, A1, A2)                                     \
                if (ba < rp[ND + 1] && ba + 32 > rp[ND]) {                            \
                    const int klo = rp[ND] - ba, khi = rp[ND + 1] - ba;               \
                    short8 bq;                                                        \
                    if (klo <= 0 && khi >= 32) {                                      \
                        bq = braw;                                                    \
                    } else {                                                          \
                        _Pragma("unroll")                                             \
                        for (int j = 0; j < 8; ++j)                                   \
                            bq[j] = (kb + j >= klo && kb + j < khi) ? braw[j] : (short)0; \
                    }                                                                 \
                    A0 = __builtin_amdgcn_mfma_f32_16x16x32_bf16(f0, bq, A0, 0, 0, 0);\
                    A1 = __builtin_amdgcn_mfma_f32_16x16x32_bf16(f1, bq, A1, 0, 0, 0);\
                    A2 = __builtin_amdgcn_mfma_f32_16x16x32_bf16(f2, bq, A2, 0, 0, 0);\
                }
                NODE_STEP(0, a00, a01, a02)
                NODE_STEP(1, a10, a11, a12)
                NODE_STEP(2, a20, a21, a22)
                NODE_STEP(3, a30, a31, a32)
                #undef NODE_STEP
            }

            #define NODE_STORE(ND, A0, A1, A2)                                        \
            {                                                                         \
                unsigned short* tp = &tile[4 * w + ND][0];                            \
                _Pragma("unroll")                                                     \
                for (int i = 0; i < 4; ++i) {                                         \
                    int p = g * 4 + i;                                                \
                    tp[(p >> 2) * 64 + (p & 3) * 16 + x] = f2bf(A0[i]);               \
                }                                                                     \
                _Pragma("unroll")                                                     \
                for (int i = 0; i < 4; ++i) {                                         \
                    int p = 16 + g * 4 + i;                                           \
                    tp[(p >> 2) * 64 + (p & 3) * 16 + x] = f2bf(A1[i]);               \
                }                                                                     \
                if (g < 2) {                                                          \
                    _Pragma("unroll")                                                 \
                    for (int i = 0; i < 4; ++i) {                                     \
                        int p = 32 + g * 4 + i;                                       \
                        tp[(p >> 2) * 64 + (p & 3) * 16 + x] = f2bf(A2[i]);           \
                    }                                                                 \
                }                                                                     \
                if (lane < SUB)      tp[640 + lane] = si16[(size_t)(base + ND) * SUB + lane]; \
                else if (lane < 32)  tp[640 + lane] = 0;                              \
            }
            NODE_STORE(0, a00, a01, a02)
            NODE_STORE(1, a10, a11, a12)
            NODE_STORE(2, a20, a21, a22)
            NODE_STORE(3, a30, a31, a32)
            #undef NODE_STORE
            __syncthreads();

            // ---- Phase B: MFMA MLP ----
            const int r = x;
            const short* Bp = w0f + ((size_t)l * NKK * 256 + w * 64 + lane) * 8;
            float bv = b0[l * HD + w * 16 + r];
            float4v accA = {bv, bv, bv, bv};
            float4v accB = {0.f, 0.f, 0.f, 0.f};
            #pragma unroll 5
            for (int kk = 0; kk < 20; kk += 2) {
                short8 aA = *(const short8*)((const short*)&tile[r][kk * 32 + g * 8]);
                short8 bA = *(const short8*)(Bp + (size_t)kk * 2048);
                accA = __builtin_amdgcn_mfma_f32_16x16x32_bf16(aA, bA, accA, 0, 0, 0);
                short8 aB = *(const short8*)((const short*)&tile[r][(kk + 1) * 32 + g * 8]);
                short8 bB = *(const short8*)(Bp + (size_t)(kk + 1) * 2048);
                accB = __builtin_amdgcn_mfma_f32_16x16x32_bf16(aB, bB, accB, 0, 0, 0);
            }
            {
                short8 a = *(const short8*)((const short*)&tile[r][20 * 32 + g * 8]);
                short8 b = *(const short8*)(Bp + (size_t)20 * 2048);
                accA = __builtin_amdgcn_mfma_f32_16x16x32_bf16(a, b, accA, 0, 0, 0);
            }
            __syncthreads();   // tile reads done before h1 overlays it
            #pragma unroll
            for (int i = 0; i < 4; ++i)
                h1[g * 4 + i][w * 16 + r] = f2bf(ssp(accA[i] + accB[i]));
            __syncthreads();

            bv = b1[l * HD + w * 16 + r];
            float4v acc1v = {bv, bv, bv, bv};
            #pragma unroll
            for (int kk = 0; kk < 2; ++kk) {
                short8 a = *(const short8*)((const short*)&h1[r][kk * 32 + g * 8]);
                short8 b = *(const short8*)(w1f + ((size_t)(l * 2 + kk) * 256 + w * 64 + lane) * 8);
                acc1v = __builtin_amdgcn_mfma_f32_16x16x32_bf16(a, b, acc1v, 0, 0, 0);
            }
            #pragma unroll
            for (int i = 0; i < 4; ++i)
                h2[g * 4 + i][w * 16 + r] = f2bf(ssp(acc1v[i]));
            __syncthreads();

            bv = b2[l * DIM + w * 16 + r];
            float4v acc2v = {bv, bv, bv, bv};
            #pragma unroll
            for (int kk = 0; kk < 2; ++kk) {
                short8 a = *(const short8*)((const short*)&h2[r][kk * 32 + g * 8]);
                short8 b = *(const short8*)(w2f + ((size_t)(l * 2 + kk) * 256 + w * 64 + lane) * 8);
                acc2v = __builtin_amdgcn_mfma_f32_16x16x32_bf16(a, b, acc2v, 0, 0, 0);
            }
            #pragma unroll
            for (int i = 0; i < 4; ++i) {
                size_t idx = (size_t)(n0 + g * 4 + i) * DIM + w * 16 + r;
                float nv = xi[idx] + acc2v[i];
                xi[idx] = nv;
                xi_s[g * 4 + i][w * 16 + r] = nv;
            }

            // h(l+1) epilogue via MFMA
            if (l + 1 < LAYERS) {
                __syncthreads();
                if (w < 2) {
                    const float* bs = bsm + (l + 1) * 2 * SUB;
                    float bv2 = bs[w * 16 + x];
                    float4v hacc = {bv2, bv2, bv2, bv2};
                    #pragma unroll
                    for (int kk = 0; kk < 2; ++kk) {
                        short8 af;
                        #pragma unroll
                        for (int j = 0; j < 8; ++j)
                            af[j] = (short)f2bf(xi_s[x][kk * 32 + g * 8 + j]);
                        short8 bf = *(const short8*)(wsmf +
                            ((((size_t)(l + 1) * 2 + kk) * 2 + w) * 64 + lane) * 8);
                        hacc = __builtin_amdgcn_mfma_f32_16x16x32_bf16(af, bf, hacc, 0, 0, 0);
                    }
                    #pragma unroll
                    for (int i = 0; i < 4; ++i) {
                        int n = n0 + g * 4 + i;
                        unsigned short v = f2bf(hacc[i]);
                        if (w == 0) si16[(size_t)n * SUB + x] = v;
                        else        mi_wr[(size_t)n * SUB + x] = v;
                    }
                }
            }
            __syncthreads();   // LDS reuse safe before next tile
        }

        if (l < LAYERS - 1) grid_barrier(&bars[1 + l]);
    }
}

extern "C" void kernel_launch(void* const* d_in, const int* in_sizes, int n_in,
                              void* d_out, int out_size, void* d_ws, size_t ws_size,
                              hipStream_t stream) {
    const int*   species = (const int*)  d_in[0];
    const int*   esrc    = (const int*)  d_in[1];
    const int*   edst    = (const int*)  d_in[2];
    const float* dist    = (const float*)d_in[3];
    const float* sw      = (const float*)d_in[4];
    const float* bo      = (const float*)d_in[5];
    const float* Wsp     = (const float*)d_in[6];
    const float* Wsm     = (const float*)d_in[7];
    const float* bsm     = (const float*)d_in[8];
    const float* w0      = (const float*)d_in[9];
    const float* b0      = (const float*)d_in[10];
    const float* w1      = (const float*)d_in[11];
    const float* b1      = (const float*)d_in[12];
    const float* w2      = (const float*)d_in[13];
    const float* b2      = (const float*)d_in[14];

    float* xi = (float*)d_out;   // N x 64 fp32, updated in place

    // ws layout: uTi | mi0 | mi1 | si16 | w0f | w1f | w2f | wsmf | rowptr | bars
    unsigned short* uTi   = (unsigned short*)d_ws;
    unsigned short* mi0   = uTi + (size_t)NCHUNK * CH_STRIDE;
    unsigned short* mi1   = mi0 + (size_t)N_NODES * SUB;
    unsigned short* si16  = mi1 + (size_t)N_NODES * SUB;
    short* w0f  = (short*)(si16 + (size_t)N_NODES * SUB);
    short* w1f  = w0f + (size_t)LAYERS * NKK * 2048;
    short* w2f  = w1f + (size_t)LAYERS * 2 * 2048;
    short* wsmf = w2f + (size_t)LAYERS * 2 * 2048;
    int* rowptr = (int*)(wsmf + (size_t)LAYERS * 2 * 2 * 512);
    int* bars   = rowptr + (N_NODES + 1);

    hipMemsetAsync(bars, 0, 4 * sizeof(int), stream);
    k_mega<<<GRID, 256, 0, stream>>>(
        species, esrc, edst, dist, sw, bo, Wsp, Wsm, bsm,
        w0, b0, w1, b1, w2, b2, xi,
        uTi, mi0, mi1, si16, w0f, w1f, w2f, wsmf, rowptr, bars);
}

// Round 18
// 570.947 us; speedup vs baseline: 1.7248x; 1.7248x over previous
//
#include <hip/hip_runtime.h>
#include <math.h>

#define N_NODES 20000
#define N_EDGES 320000
#define NCHUNK (N_EDGES / 32)      // 10000
#define CH_STRIDE 1536             // 48 p-rows * 32 edges (ush) per chunk
#define DIM 64
#define SUB 16
#define NRBF 8
#define NB 5
#define LAYERS 3
#define FCIN (NRBF*SUB*NB + SUB)   // 656
#define KPAD 672
#define NKK 21
#define HD 64
#define CUTOFF 5.0f
#define TS 680                     // LDS cat-tile row stride (ush): 2-way banks
#define GRID 1024                  // 4 blocks/CU, co-residency proven in r17
#define NTILES (N_NODES / 16)      // 1250

typedef __attribute__((ext_vector_type(8))) short short8;
typedef __attribute__((ext_vector_type(4))) float float4v;

__device__ __forceinline__ float ssp(float x) {
    float sp = fmaxf(x, 0.0f) + log1pf(expf(-fabsf(x)));
    return sp - 0.69314718055994530942f;
}

__device__ __forceinline__ unsigned short f2bf(float x) {
    unsigned int u = __float_as_uint(x);
    unsigned int r = (u + 0x7FFFu + ((u >> 16) & 1u)) >> 16;
    return (unsigned short)r;
}

// Grid barrier, invalidation-safe: RELAXED spin (no per-poll cache invalidate),
// one release fence before arrival, one acquire fence after the count trips.
__device__ __forceinline__ void grid_barrier(int* bar) {
    __syncthreads();
    if (threadIdx.x == 0) {
        __threadfence();   // release: write back our xi/si/mi stores
        __hip_atomic_fetch_add(bar, 1, __ATOMIC_RELAXED, __HIP_MEMORY_SCOPE_AGENT);
        while (__hip_atomic_load(bar, __ATOMIC_RELAXED, __HIP_MEMORY_SCOPE_AGENT) < GRID)
            __builtin_amdgcn_s_sleep(32);
        __builtin_amdgcn_fence(__ATOMIC_ACQUIRE, "agent");   // single invalidate
    }
    __syncthreads();
}

__global__ __launch_bounds__(256, 4) void k_mega(
    const int* __restrict__ species, const int* __restrict__ esrc,
    const int* __restrict__ edst, const float* __restrict__ dist,
    const float* __restrict__ sw, const float* __restrict__ bo,
    const float* __restrict__ Wsp, const float* __restrict__ Wsm,
    const float* __restrict__ bsm,
    const float* __restrict__ w0, const float* __restrict__ b0,
    const float* __restrict__ w1, const float* __restrict__ b1,
    const float* __restrict__ w2, const float* __restrict__ b2,
    float* __restrict__ xi,
    unsigned short* __restrict__ uTi,
    unsigned short* __restrict__ mi0, unsigned short* __restrict__ mi1,
    unsigned short* __restrict__ si16,
    short* __restrict__ w0f, short* __restrict__ w1f, short* __restrict__ w2f,
    short* __restrict__ wsmf, int* __restrict__ rowptr, int* __restrict__ bars)
{
    __shared__ __align__(16) unsigned short tile[16][TS];    // 21760 B
    __shared__ float xs[8][64];                              // 2048 B (setup)
    __shared__ int t_sh;
    unsigned short (*h1)[72] = (unsigned short (*)[72])((char*)tile);
    unsigned short (*h2)[72] = (unsigned short (*)[72])((char*)tile + 4608);
    float (*xi_s)[68]        = (float (*)[68])((char*)tile + 9216);

    const int tid = threadIdx.x;
    const int gid = blockIdx.x * 256 + tid;
    int* tickets = bars + 4;

    // ================= setup (partitioned across the grid) =================
    if (gid <= N_NODES) {                       // rowptr
        int a = 0, b = N_EDGES;
        while (a < b) { int m = (a + b) >> 1; if (esrc[m] < gid) a = m + 1; else b = m; }
        rowptr[gid] = a;
    }
    {                                           // pack w0/w1/w2
        const int SZ0 = LAYERS * NKK * 4 * 64 * 8;
        const int SZ12 = LAYERS * 2 * 4 * 64 * 8;
        int i = gid;
        if (i < SZ0) {
            int j = i & 7, t = i >> 3;
            int lane = t & 63; t >>= 6;
            int nf = t & 3; t >>= 2;
            int kk = t % NKK, l = t / NKK;
            int kp = kk * 32 + (lane >> 4) * 8 + j;
            int col = nf * 16 + (lane & 15);
            float v = 0.0f;
            if (kp < FCIN) {
                int orig;
                if (kp < 640) {
                    int j10 = kp >> 6, rem = kp & 63, g = rem >> 4, s = rem & 15;
                    int p = g + 4 * j10;
                    orig = (p / 5) * 80 + s * 5 + (p - 5 * (p / 5));
                } else orig = kp;
                v = w0[((size_t)l * FCIN + orig) * HD + col];
            }
            w0f[i] = (short)f2bf(v);
        } else if (i - SZ0 < 2 * SZ12) {
            i -= SZ0;
            const float* W = (i < SZ12) ? w1 : w2;
            short* Wf = (i < SZ12) ? w1f : w2f;
            int ii = (i < SZ12) ? i : i - SZ12;
            int j = ii & 7, t = ii >> 3;
            int lane = t & 63; t >>= 6;
            int nf = t & 3; t >>= 2;
            int kk = t & 1, l = t >> 1;
            int kp = kk * 32 + (lane >> 4) * 8 + j;
            int col = nf * 16 + (lane & 15);
            Wf[ii] = (short)f2bf(W[((size_t)l * HD + kp) * HD + col]);
        }
    }
    if (gid < LAYERS * 2 * 2 * 512) {           // pack Wsm for h-GEMM
        int i = gid;
        int j = i & 7, t = i >> 3;
        int lane = t & 63; t >>= 6;
        int nf = t & 1; t >>= 1;
        int kk = t & 1, l = t >> 1;
        int kp = kk * 32 + (lane >> 4) * 8 + j;
        int col = nf * 16 + (lane & 15);
        wsmf[i] = (short)f2bf(Wsm[(size_t)l * DIM * 2 * SUB + kp * 2 * SUB + col]);
    }
    for (int e = gid; e < N_EDGES; e += GRID * 256) {   // uTi (chunk-tiled)
        float d = dist[e];
        float s = sw[e];
        float rbv[NRBF], bov[NB];
        #pragma unroll
        for (int r = 0; r < NRBF; ++r) {
            float mu = (CUTOFF / (NRBF - 1)) * (float)r;
            float z = (d - mu) * ((float)NRBF / CUTOFF);
            rbv[r] = s * expf(-0.5f * z * z);
        }
        #pragma unroll
        for (int b = 0; b < NB; ++b) bov[b] = bo[e * NB + b];
        unsigned short* out = uTi + (size_t)(e >> 5) * CH_STRIDE + (e & 31);
        #pragma unroll
        for (int p = 0; p < 48; ++p) {
            float v = (p < 40) ? rbv[p / 5] * bov[p % 5] : 0.0f;
            out[p * 32] = f2bf(v);
        }
    }
    for (int nb = blockIdx.x; nb < N_NODES / 8; nb += GRID) {   // init xi + h(0)
        const int nl = tid >> 5, j = tid & 31;
        const int n = nb * 8 + nl;
        const int sp = species[n];
        float v0 = Wsp[sp * DIM + j];
        float v1 = Wsp[sp * DIM + 32 + j];
        xi[(size_t)n * DIM + j] = v0;
        xi[(size_t)n * DIM + 32 + j] = v1;
        xs[nl][j] = v0;
        xs[nl][32 + j] = v1;
        __syncthreads();
        float v = bsm[j];
        const float* xr = &xs[nl][0];
        #pragma unroll 8
        for (int d = 0; d < DIM; ++d) v = fmaf(xr[d], Wsm[d * 2 * SUB + j], v);
        if (j < SUB) si16[(size_t)n * SUB + j] = f2bf(v);
        else         mi0[(size_t)n * SUB + (j - SUB)] = f2bf(v);
        __syncthreads();
    }
    grid_barrier(&bars[0]);

    // ================= layers =================
    const int lane = tid & 63;
    const int w = tid >> 6;
    const int x = lane & 15, g = lane >> 4;

    for (int l = 0; l < LAYERS; ++l) {
        const unsigned short* mi_rd = (l & 1) ? mi1 : mi0;
        unsigned short* mi_wr = (l & 1) ? mi0 : mi1;

        while (true) {
            if (tid == 0)
                t_sh = __hip_atomic_fetch_add(&tickets[l], 1, __ATOMIC_RELAXED,
                                              __HIP_MEMORY_SCOPE_AGENT);
            __syncthreads();
            const int t = t_sh;
            if (t >= NTILES) break;
            const int n0 = t * 16;

            // ---- Phase A: union-sweep MFMA aggregation into LDS tile ----
            const unsigned short* mx = mi_rd + x;
            const int base = n0 + 4 * w;
            int rp[5];
            #pragma unroll
            for (int i = 0; i < 5; ++i) rp[i] = rowptr[base + i];

            float4v a00={0,0,0,0}, a01={0,0,0,0}, a02={0,0,0,0};
            float4v a10={0,0,0,0}, a11={0,0,0,0}, a12={0,0,0,0};
            float4v a20={0,0,0,0}, a21={0,0,0,0}, a22={0,0,0,0};
            float4v a30={0,0,0,0}, a31={0,0,0,0}, a32={0,0,0,0};

            const int kb = g * 8;
            for (int ba = rp[0] & ~31; ba < rp[4]; ba += 32) {
                int4 i0 = *(const int4*)(edst + ba + kb);
                int4 i1 = *(const int4*)(edst + ba + kb + 4);
                short8 braw;
                braw[0] = (short)mx[(size_t)i0.x * 16];
                braw[1] = (short)mx[(size_t)i0.y * 16];
                braw[2] = (short)mx[(size_t)i0.z * 16];
                braw[3] = (short)mx[(size_t)i0.w * 16];
                braw[4] = (short)mx[(size_t)i1.x * 16];
                braw[5] = (short)mx[(size_t)i1.y * 16];
                braw[6] = (short)mx[(size_t)i1.z * 16];
                braw[7] = (short)mx[(size_t)i1.w * 16];

                const unsigned short* ap = uTi + (size_t)(ba >> 5) * CH_STRIDE + x * 32 + kb;
                short8 f0 = *(const short8*)(ap);
                short8 f1 = *(const short8*)(ap + 512);
                short8 f2 = *(const short8*)(ap + 1024);

                #define NODE_STEP(ND, A0, A1, A2)                                     \
                if (ba < rp[ND + 1] && ba + 32 > rp[ND]) {                            \
                    const int klo = rp[ND] - ba, khi = rp[ND + 1] - ba;               \
                    short8 bq;                                                        \
                    if (klo <= 0 && khi >= 32) {                                      \
                        bq = braw;                                                    \
                    } else {                                                          \
                        _Pragma("unroll")                                             \
                        for (int j = 0; j < 8; ++j)                                   \
                            bq[j] = (kb + j >= klo && kb + j < khi) ? braw[j] : (short)0; \
                    }                                                                 \
                    A0 = __builtin_amdgcn_mfma_f32_16x16x32_bf16(f0, bq, A0, 0, 0, 0);\
                    A1 = __builtin_amdgcn_mfma_f32_16x16x32_bf16(f1, bq, A1, 0, 0, 0);\
                    A2 = __builtin_amdgcn_mfma_f32_16x16x32_bf16(f2, bq, A2, 0, 0, 0);\
                }
                NODE_STEP(0, a00, a01, a02)
                NODE_STEP(1, a10, a11, a12)
                NODE_STEP(2, a20, a21, a22)
                NODE_STEP(3, a30, a31, a32)
                #undef NODE_STEP
            }

            #define NODE_STORE(ND, A0, A1, A2)                                        \
            {                                                                         \
                unsigned short* tp = &tile[4 * w + ND][0];                            \
                _Pragma("unroll")                                                     \
                for (int i = 0; i < 4; ++i) {                                         \
                    int p = g * 4 + i;                                                \
                    tp[(p >> 2) * 64 + (p & 3) * 16 + x] = f2bf(A0[i]);               \
                }                                                                     \
                _Pragma("unroll")                                                     \
                for (int i = 0; i < 4; ++i) {                                         \
                    int p = 16 + g * 4 + i;                                           \
                    tp[(p >> 2) * 64 + (p & 3) * 16 + x] = f2bf(A1[i]);               \
                }                                                                     \
                if (g < 2) {                                                          \
                    _Pragma("unroll")                                                 \
                    for (int i = 0; i < 4; ++i) {                                     \
                        int p = 32 + g * 4 + i;                                       \
                        tp[(p >> 2) * 64 + (p & 3) * 16 + x] = f2bf(A2[i]);           \
                    }                                                                 \
                }                                                                     \
                if (lane < SUB)      tp[640 + lane] = si16[(size_t)(base + ND) * SUB + lane]; \
                else if (lane < 32)  tp[640 + lane] = 0;                              \
            }
            NODE_STORE(0, a00, a01, a02)
            NODE_STORE(1, a10, a11, a12)
            NODE_STORE(2, a20, a21, a22)
            NODE_STORE(3, a30, a31, a32)
            #undef NODE_STORE
            __syncthreads();

            // ---- Phase B: MFMA MLP ----
            const int r = x;
            const short* Bp = w0f + ((size_t)l * NKK * 256 + w * 64 + lane) * 8;
            float bv = b0[l * HD + w * 16 + r];
            float4v accA = {bv, bv, bv, bv};
            float4v accB = {0.f, 0.f, 0.f, 0.f};
            #pragma unroll 5
            for (int kk = 0; kk < 20; kk += 2) {
                short8 aA = *(const short8*)((const short*)&tile[r][kk * 32 + g * 8]);
                short8 bA = *(const short8*)(Bp + (size_t)kk * 2048);
                accA = __builtin_amdgcn_mfma_f32_16x16x32_bf16(aA, bA, accA, 0, 0, 0);
                short8 aB = *(const short8*)((const short*)&tile[r][(kk + 1) * 32 + g * 8]);
                short8 bB = *(const short8*)(Bp + (size_t)(kk + 1) * 2048);
                accB = __builtin_amdgcn_mfma_f32_16x16x32_bf16(aB, bB, accB, 0, 0, 0);
            }
            {
                short8 a = *(const short8*)((const short*)&tile[r][20 * 32 + g * 8]);
                short8 b = *(const short8*)(Bp + (size_t)20 * 2048);
                accA = __builtin_amdgcn_mfma_f32_16x16x32_bf16(a, b, accA, 0, 0, 0);
            }
            __syncthreads();   // tile reads done before h1 overlays it
            #pragma unroll
            for (int i = 0; i < 4; ++i)
                h1[g * 4 + i][w * 16 + r] = f2bf(ssp(accA[i] + accB[i]));
            __syncthreads();

            bv = b1[l * HD + w * 16 + r];
            float4v acc1v = {bv, bv, bv, bv};
            #pragma unroll
            for (int kk = 0; kk < 2; ++kk) {
                short8 a = *(const short8*)((const short*)&h1[r][kk * 32 + g * 8]);
                short8 b = *(const short8*)(w1f + ((size_t)(l * 2 + kk) * 256 + w * 64 + lane) * 8);
                acc1v = __builtin_amdgcn_mfma_f32_16x16x32_bf16(a, b, acc1v, 0, 0, 0);
            }
            #pragma unroll
            for (int i = 0; i < 4; ++i)
                h2[g * 4 + i][w * 16 + r] = f2bf(ssp(acc1v[i]));
            __syncthreads();

            bv = b2[l * DIM + w * 16 + r];
            float4v acc2v = {bv, bv, bv, bv};
            #pragma unroll
            for (int kk = 0; kk < 2; ++kk) {
                short8 a = *(const short8*)((const short*)&h2[r][kk * 32 + g * 8]);
                short8 b = *(const short8*)(w2f + ((size_t)(l * 2 + kk) * 256 + w * 64 + lane) * 8);
                acc2v = __builtin_amdgcn_mfma_f32_16x16x32_bf16(a, b, acc2v, 0, 0, 0);
            }
            #pragma unroll
            for (int i = 0; i < 4; ++i) {
                size_t idx = (size_t)(n0 + g * 4 + i) * DIM + w * 16 + r;
                float nv = xi[idx] + acc2v[i];
                xi[idx] = nv;
                xi_s[g * 4 + i][w * 16 + r] = nv;
            }

            // h(l+1) epilogue via MFMA
            if (l + 1 < LAYERS) {
                __syncthreads();
                if (w < 2) {
                    const float* bs = bsm + (l + 1) * 2 * SUB;
                    float bv2 = bs[w * 16 + x];
                    float4v hacc = {bv2, bv2, bv2, bv2};
                    #pragma unroll
                    for (int kk = 0; kk < 2; ++kk) {
                        short8 af;
                        #pragma unroll
                        for (int j = 0; j < 8; ++j)
                            af[j] = (short)f2bf(xi_s[x][kk * 32 + g * 8 + j]);
                        short8 bf = *(const short8*)(wsmf +
                            ((((size_t)(l + 1) * 2 + kk) * 2 + w) * 64 + lane) * 8);
                        hacc = __builtin_amdgcn_mfma_f32_16x16x32_bf16(af, bf, hacc, 0, 0, 0);
                    }
                    #pragma unroll
                    for (int i = 0; i < 4; ++i) {
                        int n = n0 + g * 4 + i;
                        unsigned short v = f2bf(hacc[i]);
                        if (w == 0) si16[(size_t)n * SUB + x] = v;
                        else        mi_wr[(size_t)n * SUB + x] = v;
                    }
                }
            }
            __syncthreads();   // LDS + t_sh reuse safe before next ticket
        }

        if (l < LAYERS - 1) grid_barrier(&bars[1 + l]);
    }
}

extern "C" void kernel_launch(void* const* d_in, const int* in_sizes, int n_in,
                              void* d_out, int out_size, void* d_ws, size_t ws_size,
                              hipStream_t stream) {
    const int*   species = (const int*)  d_in[0];
    const int*   esrc    = (const int*)  d_in[1];
    const int*   edst    = (const int*)  d_in[2];
    const float* dist    = (const float*)d_in[3];
    const float* sw      = (const float*)d_in[4];
    const float* bo      = (const float*)d_in[5];
    const float* Wsp     = (const float*)d_in[6];
    const float* Wsm     = (const float*)d_in[7];
    const float* bsm     = (const float*)d_in[8];
    const float* w0      = (const float*)d_in[9];
    const float* b0      = (const float*)d_in[10];
    const float* w1      = (const float*)d_in[11];
    const float* b1      = (const float*)d_in[12];
    const float* w2      = (const float*)d_in[13];
    const float* b2      = (const float*)d_in[14];

    float* xi = (float*)d_out;   // N x 64 fp32, updated in place

    // ws layout: uTi | mi0 | mi1 | si16 | w0f | w1f | w2f | wsmf | rowptr | bars+tickets
    unsigned short* uTi   = (unsigned short*)d_ws;
    unsigned short* mi0   = uTi + (size_t)NCHUNK * CH_STRIDE;
    unsigned short* mi1   = mi0 + (size_t)N_NODES * SUB;
    unsigned short* si16  = mi1 + (size_t)N_NODES * SUB;
    short* w0f  = (short*)(si16 + (size_t)N_NODES * SUB);
    short* w1f  = w0f + (size_t)LAYERS * NKK * 2048;
    short* w2f  = w1f + (size_t)LAYERS * 2 * 2048;
    short* wsmf = w2f + (size_t)LAYERS * 2 * 2048;
    int* rowptr = (int*)(wsmf + (size_t)LAYERS * 2 * 2 * 512);
    int* bars   = rowptr + (N_NODES + 1);

    hipMemsetAsync(bars, 0, 8 * sizeof(int), stream);   // 4 barriers + 4 tickets
    k_mega<<<GRID, 256, 0, stream>>>(
        species, esrc, edst, dist, sw, bo, Wsp, Wsm, bsm,
        w0, b0, w1, b1, w2, b2, xi,
        uTi, mi0, mi1, si16, w0f, w1f, w2f, wsmf, rowptr, bars);
}

// Round 19
// 92.928 us; speedup vs baseline: 10.5973x; 6.1440x over previous
//
#include <hip/hip_runtime.h>
#include <math.h>

#define N_NODES 20000
#define N_EDGES 320000
#define NCHUNK (N_EDGES / 32)      // 10000
#define CH_STRIDE 1536             // 48 p-rows * 32 edges (ush) per chunk
#define DIM 64
#define SUB 16
#define NRBF 8
#define NB 5
#define LAYERS 3
#define FCIN (NRBF*SUB*NB + SUB)   // 656
#define KPAD 672
#define NKK 21
#define HD 64
#define CUTOFF 5.0f
#define TS 680                     // LDS cat-tile row stride (ush): 2-way banks

// k_setup block-range sizes
#define B_ROWPTR 79                // ceil(20001/256)
#define B_PACKW  600               // (129024 + 24576) / 256
#define B_PACKSM 24                // 6144 / 256
#define B_U      1250              // N_EDGES / 256
#define B_INIT   2500              // N_NODES / 8

typedef __attribute__((ext_vector_type(8))) short short8;
typedef __attribute__((ext_vector_type(4))) float float4v;

__device__ __forceinline__ float ssp(float x) {
    float sp = fmaxf(x, 0.0f) + log1pf(expf(-fabsf(x)));
    return sp - 0.69314718055994530942f;
}

__device__ __forceinline__ unsigned short f2bf(float x) {
    unsigned int u = __float_as_uint(x);
    unsigned int r = (u + 0x7FFFu + ((u >> 16) & 1u)) >> 16;
    return (unsigned short)r;
}

// --- single setup kernel: rowptr | packw | pack Wsm | uTi | init ------------
__global__ __launch_bounds__(256) void k_setup(
    const int* __restrict__ esrc, int* __restrict__ rowptr,
    const float* __restrict__ w0, const float* __restrict__ w1,
    const float* __restrict__ w2,
    short* __restrict__ w0f, short* __restrict__ w1f, short* __restrict__ w2f,
    const float* __restrict__ Wsm, short* __restrict__ wsmf,
    const float* __restrict__ dist, const float* __restrict__ sw,
    const float* __restrict__ bo, unsigned short* __restrict__ uTi,
    const int* __restrict__ species, const float* __restrict__ Wsp,
    const float* __restrict__ bsm, float* __restrict__ xi,
    unsigned short* __restrict__ si16, unsigned short* __restrict__ mi16)
{
    __shared__ float xs[8][64];
    const unsigned bid = blockIdx.x;

    if (bid < B_ROWPTR) {                       // ---- rowptr ----
        int n = bid * 256 + threadIdx.x;
        if (n > N_NODES) return;
        int a = 0, b = N_EDGES;
        while (a < b) { int m = (a + b) >> 1; if (esrc[m] < n) a = m + 1; else b = m; }
        rowptr[n] = a;
        return;
    }
    if (bid < B_ROWPTR + B_PACKW) {             // ---- pack w0/w1/w2 ----
        const int SZ0 = LAYERS * NKK * 4 * 64 * 8;
        const int SZ12 = LAYERS * 2 * 4 * 64 * 8;
        int i = (bid - B_ROWPTR) * 256 + threadIdx.x;
        if (i < SZ0) {
            int j = i & 7, t = i >> 3;
            int lane = t & 63; t >>= 6;
            int nf = t & 3; t >>= 2;
            int kk = t % NKK, l = t / NKK;
            int kp = kk * 32 + (lane >> 4) * 8 + j;
            int col = nf * 16 + (lane & 15);
            float v = 0.0f;
            if (kp < FCIN) {
                int orig;
                if (kp < 640) {
                    int j10 = kp >> 6, rem = kp & 63, g = rem >> 4, s = rem & 15;
                    int p = g + 4 * j10;
                    orig = (p / 5) * 80 + s * 5 + (p - 5 * (p / 5));
                } else orig = kp;
                v = w0[((size_t)l * FCIN + orig) * HD + col];
            }
            w0f[i] = (short)f2bf(v);
            return;
        }
        i -= SZ0;
        if (i < 2 * SZ12) {
            const float* W = (i < SZ12) ? w1 : w2;
            short* Wf = (i < SZ12) ? w1f : w2f;
            int ii = (i < SZ12) ? i : i - SZ12;
            int j = ii & 7, t = ii >> 3;
            int lane = t & 63; t >>= 6;
            int nf = t & 3; t >>= 2;
            int kk = t & 1, l = t >> 1;
            int kp = kk * 32 + (lane >> 4) * 8 + j;
            int col = nf * 16 + (lane & 15);
            Wf[ii] = (short)f2bf(W[((size_t)l * HD + kp) * HD + col]);
        }
        return;
    }
    if (bid < B_ROWPTR + B_PACKW + B_PACKSM) {  // ---- pack Wsm for h-GEMM ----
        int i = (bid - B_ROWPTR - B_PACKW) * 256 + threadIdx.x;   // < 6144
        int j = i & 7, t = i >> 3;
        int lane = t & 63; t >>= 6;
        int nf = t & 1; t >>= 1;
        int kk = t & 1, l = t >> 1;
        int kp = kk * 32 + (lane >> 4) * 8 + j;
        int col = nf * 16 + (lane & 15);
        wsmf[i] = (short)f2bf(Wsm[(size_t)l * DIM * 2 * SUB + kp * 2 * SUB + col]);
        return;
    }
    if (bid < B_ROWPTR + B_PACKW + B_PACKSM + B_U) {   // ---- uTi (chunk-tiled) ----
        int e = (bid - B_ROWPTR - B_PACKW - B_PACKSM) * 256 + threadIdx.x;
        float d = dist[e];
        float s = sw[e];
        float rbv[NRBF], bov[NB];
        #pragma unroll
        for (int r = 0; r < NRBF; ++r) {
            float mu = (CUTOFF / (NRBF - 1)) * (float)r;
            float z = (d - mu) * ((float)NRBF / CUTOFF);
            rbv[r] = s * expf(-0.5f * z * z);
        }
        #pragma unroll
        for (int b = 0; b < NB; ++b) bov[b] = bo[e * NB + b];
        unsigned short* out = uTi + (size_t)(e >> 5) * CH_STRIDE + (e & 31);
        #pragma unroll
        for (int p = 0; p < 48; ++p) {
            float v = (p < 40) ? rbv[p / 5] * bov[p % 5] : 0.0f;
            out[p * 32] = f2bf(v);
        }
        return;
    }
    {                                            // ---- init xi + h(0) ----
        int blk = bid - (B_ROWPTR + B_PACKW + B_PACKSM + B_U);
        const int nl = threadIdx.x >> 5, j = threadIdx.x & 31;
        const int n = blk * 8 + nl;
        const int sp = species[n];
        float v0 = Wsp[sp * DIM + j];
        float v1 = Wsp[sp * DIM + 32 + j];
        xi[(size_t)n * DIM + j] = v0;
        xi[(size_t)n * DIM + 32 + j] = v1;
        xs[nl][j] = v0;
        xs[nl][32 + j] = v1;
        __syncthreads();
        float v = bsm[j];
        const float* xr = &xs[nl][0];
        #pragma unroll 8
        for (int d = 0; d < DIM; ++d) v = fmaf(xr[d], Wsm[d * 2 * SUB + j], v);
        if (j < SUB) si16[(size_t)n * SUB + j] = f2bf(v);
        else         mi16[(size_t)n * SUB + (j - SUB)] = f2bf(v);
    }
}

// --- fused per-layer kernel -------------------------------------------------
// Block = 16 nodes, 4 waves.
// Phase A: union-sweep MFMA aggregation; A-frags from chunk-tiled uTi (wave
//   reads one CONTIGUOUS 1KB block per p-tile -> 1-segment transactions).
// Phase B: fc0 (A from LDS tile) -> fc1 -> fc2 + residual -> MFMA h-epilogue.
__global__ __launch_bounds__(256) void k_layer(
    const int* __restrict__ rowptr, const int* __restrict__ edst,
    const unsigned short* __restrict__ uTi,
    const unsigned short* __restrict__ mi_rd,
    unsigned short* __restrict__ mi_wr,
    unsigned short* __restrict__ si16,
    const short* __restrict__ w0f, const float* __restrict__ b0,
    const short* __restrict__ w1f, const float* __restrict__ b1,
    const short* __restrict__ w2f, const float* __restrict__ b2,
    const short* __restrict__ wsmf, const float* __restrict__ bsm,
    float* __restrict__ xi, int l)
{
    __shared__ __align__(16) unsigned short tile[16][TS];    // 21760 B total LDS
    unsigned short (*h1)[72] = (unsigned short (*)[72])((char*)tile);          // 2304 B
    unsigned short (*h2)[72] = (unsigned short (*)[72])((char*)tile + 4608);   // 2304 B
    float (*xi_s)[68]        = (float (*)[68])((char*)tile + 9216);            // 4352 B

    const int lane = threadIdx.x & 63;
    const int w = threadIdx.x >> 6;
    const int n0 = blockIdx.x * 16;
    const int x = lane & 15, g = lane >> 4;

    // ---- Phase A: union-sweep MFMA aggregation into LDS tile ----
    const unsigned short* mx = mi_rd + x;
    const int base = n0 + 4 * w;
    int rp[5];
    {
        int4 r4 = *(const int4*)(rowptr + base);   // base % 4 == 0 -> 16B aligned
        rp[0] = r4.x; rp[1] = r4.y; rp[2] = r4.z; rp[3] = r4.w;
        rp[4] = rowptr[base + 4];
    }

    float4v a00={0,0,0,0}, a01={0,0,0,0}, a02={0,0,0,0};
    float4v a10={0,0,0,0}, a11={0,0,0,0}, a12={0,0,0,0};
    float4v a20={0,0,0,0}, a21={0,0,0,0}, a22={0,0,0,0};
    float4v a30={0,0,0,0}, a31={0,0,0,0}, a32={0,0,0,0};

    const int kb = g * 8;
    for (int ba = rp[0] & ~31; ba < rp[4]; ba += 32) {
        // shared loads for this chunk (once per chunk, all 4 nodes)
        int4 i0 = *(const int4*)(edst + ba + kb);
        int4 i1 = *(const int4*)(edst + ba + kb + 4);
        // all edst entries are valid node indices (chunk within [0,N_EDGES))
        short8 braw;
        braw[0] = (short)mx[(size_t)i0.x * 16];
        braw[1] = (short)mx[(size_t)i0.y * 16];
        braw[2] = (short)mx[(size_t)i0.z * 16];
        braw[3] = (short)mx[(size_t)i0.w * 16];
        braw[4] = (short)mx[(size_t)i1.x * 16];
        braw[5] = (short)mx[(size_t)i1.y * 16];
        braw[6] = (short)mx[(size_t)i1.z * 16];
        braw[7] = (short)mx[(size_t)i1.w * 16];

        // A-frags: contiguous 1KB per p-tile across the wave
        const unsigned short* ap = uTi + (size_t)(ba >> 5) * CH_STRIDE + x * 32 + kb;
        short8 f0 = *(const short8*)(ap);
        short8 f1 = *(const short8*)(ap + 512);
        short8 f2 = *(const short8*)(ap + 1024);

        #define NODE_STEP(ND, A0, A1, A2)                                     \
        if (ba < rp[ND + 1] && ba + 32 > rp[ND]) {                            \
            const int klo = rp[ND] - ba, khi = rp[ND + 1] - ba;               \
            short8 bq;                                                        \
            if (klo <= 0 && khi >= 32) {                                      \
                bq = braw;                                                    \
            } else {                                                          \
                _Pragma("unroll")                                             \
                for (int j = 0; j < 8; ++j)                                   \
                    bq[j] = (kb + j >= klo && kb + j < khi) ? braw[j] : (short)0; \
            }                                                                 \
            A0 = __builtin_amdgcn_mfma_f32_16x16x32_bf16(f0, bq, A0, 0, 0, 0);\
            A1 = __builtin_amdgcn_mfma_f32_16x16x32_bf16(f1, bq, A1, 0, 0, 0);\
            A2 = __builtin_amdgcn_mfma_f32_16x16x32_bf16(f2, bq, A2, 0, 0, 0);\
        }
        NODE_STEP(0, a00, a01, a02)
        NODE_STEP(1, a10, a11, a12)
        NODE_STEP(2, a20, a21, a22)
        NODE_STEP(3, a30, a31, a32)
        #undef NODE_STEP
    }

    #define NODE_STORE(ND, A0, A1, A2)                                        \
    {                                                                         \
        unsigned short* tp = &tile[4 * w + ND][0];                            \
        _Pragma("unroll")                                                     \
        for (int i = 0; i < 4; ++i) {                                         \
            int p = g * 4 + i;                                                \
            tp[(p >> 2) * 64 + (p & 3) * 16 + x] = f2bf(A0[i]);               \
        }                                                                     \
        _Pragma("unroll")                                                     \
        for (int i = 0; i < 4; ++i) {                                         \
            int p = 16 + g * 4 + i;                                           \
            tp[(p >> 2) * 64 + (p & 3) * 16 + x] = f2bf(A1[i]);               \
        }                                                                     \
        if (g < 2) {                                                          \
            _Pragma("unroll")                                                 \
            for (int i = 0; i < 4; ++i) {                                     \
                int p = 32 + g * 4 + i;                                       \
                tp[(p >> 2) * 64 + (p & 3) * 16 + x] = f2bf(A2[i]);           \
            }                                                                 \
        }                                                                     \
        if (lane < SUB)      tp[640 + lane] = si16[(size_t)(base + ND) * SUB + lane]; \
        else if (lane < 32)  tp[640 + lane] = 0;                              \
    }
    NODE_STORE(0, a00, a01, a02)
    NODE_STORE(1, a10, a11, a12)
    NODE_STORE(2, a20, a21, a22)
    NODE_STORE(3, a30, a31, a32)
    #undef NODE_STORE
    __syncthreads();

    // ---- Phase B: MFMA MLP (A-frags from LDS tile) ----
    const int r = x;
    const short* Bp = w0f + ((size_t)l * NKK * 256 + w * 64 + lane) * 8;
    float bv = b0[l * HD + w * 16 + r];
    float4v accA = {bv, bv, bv, bv};
    float4v accB = {0.f, 0.f, 0.f, 0.f};
    #pragma unroll 5
    for (int kk = 0; kk < 20; kk += 2) {
        short8 aA = *(const short8*)((const short*)&tile[r][kk * 32 + g * 8]);
        short8 bA = *(const short8*)(Bp + (size_t)kk * 2048);
        accA = __builtin_amdgcn_mfma_f32_16x16x32_bf16(aA, bA, accA, 0, 0, 0);
        short8 aB = *(const short8*)((const short*)&tile[r][(kk + 1) * 32 + g * 8]);
        short8 bB = *(const short8*)(Bp + (size_t)(kk + 1) * 2048);
        accB = __builtin_amdgcn_mfma_f32_16x16x32_bf16(aB, bB, accB, 0, 0, 0);
    }
    {
        short8 a = *(const short8*)((const short*)&tile[r][20 * 32 + g * 8]);
        short8 b = *(const short8*)(Bp + (size_t)20 * 2048);
        accA = __builtin_amdgcn_mfma_f32_16x16x32_bf16(a, b, accA, 0, 0, 0);
    }
    __syncthreads();   // all tile reads done before h1 overlays it
    #pragma unroll
    for (int i = 0; i < 4; ++i)
        h1[g * 4 + i][w * 16 + r] = f2bf(ssp(accA[i] + accB[i]));
    __syncthreads();

    // fc1
    bv = b1[l * HD + w * 16 + r];
    float4v acc1v = {bv, bv, bv, bv};
    #pragma unroll
    for (int kk = 0; kk < 2; ++kk) {
        short8 a = *(const short8*)((const short*)&h1[r][kk * 32 + g * 8]);
        short8 b = *(const short8*)(w1f + ((size_t)(l * 2 + kk) * 256 + w * 64 + lane) * 8);
        acc1v = __builtin_amdgcn_mfma_f32_16x16x32_bf16(a, b, acc1v, 0, 0, 0);
    }
    #pragma unroll
    for (int i = 0; i < 4; ++i)
        h2[g * 4 + i][w * 16 + r] = f2bf(ssp(acc1v[i]));   // h2 disjoint from h1
    __syncthreads();

    // fc2 + residual; stage fresh xi rows for the h epilogue
    bv = b2[l * DIM + w * 16 + r];
    float4v acc2v = {bv, bv, bv, bv};
    #pragma unroll
    for (int kk = 0; kk < 2; ++kk) {
        short8 a = *(const short8*)((const short*)&h2[r][kk * 32 + g * 8]);
        short8 b = *(const short8*)(w2f + ((size_t)(l * 2 + kk) * 256 + w * 64 + lane) * 8);
        acc2v = __builtin_amdgcn_mfma_f32_16x16x32_bf16(a, b, acc2v, 0, 0, 0);
    }
    #pragma unroll
    for (int i = 0; i < 4; ++i) {
        size_t idx = (size_t)(n0 + g * 4 + i) * DIM + w * 16 + r;
        float nv = xi[idx] + acc2v[i];
        xi[idx] = nv;
        xi_s[g * 4 + i][w * 16 + r] = nv;   // xi_s disjoint from h2
    }

    // h(l+1) epilogue via MFMA: h = bf16(xi) @ bf16(Wsm[l+1]) + b (fp32 accum).
    if (l + 1 < LAYERS) {
        __syncthreads();
        if (w < 2) {
            const float* bs = bsm + (l + 1) * 2 * SUB;
            float bv2 = bs[w * 16 + x];
            float4v hacc = {bv2, bv2, bv2, bv2};
            #pragma unroll
            for (int kk = 0; kk < 2; ++kk) {
                short8 af;
                #pragma unroll
                for (int j = 0; j < 8; ++j)
                    af[j] = (short)f2bf(xi_s[x][kk * 32 + g * 8 + j]);
                short8 bf = *(const short8*)(wsmf +
                    ((((size_t)(l + 1) * 2 + kk) * 2 + w) * 64 + lane) * 8);
                hacc = __builtin_amdgcn_mfma_f32_16x16x32_bf16(af, bf, hacc, 0, 0, 0);
            }
            #pragma unroll
            for (int i = 0; i < 4; ++i) {
                int n = n0 + g * 4 + i;
                unsigned short v = f2bf(hacc[i]);
                if (w == 0) si16[(size_t)n * SUB + x] = v;
                else        mi_wr[(size_t)n * SUB + x] = v;
            }
        }
    }
}

extern "C" void kernel_launch(void* const* d_in, const int* in_sizes, int n_in,
                              void* d_out, int out_size, void* d_ws, size_t ws_size,
                              hipStream_t stream) {
    const int*   species = (const int*)  d_in[0];
    const int*   esrc    = (const int*)  d_in[1];
    const int*   edst    = (const int*)  d_in[2];
    const float* dist    = (const float*)d_in[3];
    const float* sw      = (const float*)d_in[4];
    const float* bo      = (const float*)d_in[5];
    const float* Wsp     = (const float*)d_in[6];
    const float* Wsm     = (const float*)d_in[7];
    const float* bsm     = (const float*)d_in[8];
    const float* w0      = (const float*)d_in[9];
    const float* b0      = (const float*)d_in[10];
    const float* w1      = (const float*)d_in[11];
    const float* b1      = (const float*)d_in[12];
    const float* w2      = (const float*)d_in[13];
    const float* b2      = (const float*)d_in[14];

    float* xi = (float*)d_out;   // N x 64 fp32, updated in place

    // ws layout: uTi NCHUNK*1536 ush | mi16 2 x N*16 ush | si16 N*16 ush |
    //            w0f | w1f | w2f | wsmf | rowptr
    unsigned short* uTi   = (unsigned short*)d_ws;
    unsigned short* mi0   = uTi + (size_t)NCHUNK * CH_STRIDE;
    unsigned short* mi1   = mi0 + (size_t)N_NODES * SUB;
    unsigned short* si16  = mi1 + (size_t)N_NODES * SUB;
    short* w0f  = (short*)(si16 + (size_t)N_NODES * SUB);
    short* w1f  = w0f + (size_t)LAYERS * NKK * 2048;
    short* w2f  = w1f + (size_t)LAYERS * 2 * 2048;
    short* wsmf = w2f + (size_t)LAYERS * 2 * 2048;
    int* rowptr = (int*)(wsmf + (size_t)LAYERS * 2 * 2 * 512);

    k_setup<<<B_ROWPTR + B_PACKW + B_PACKSM + B_U + B_INIT, 256, 0, stream>>>(
        esrc, rowptr, w0, w1, w2, w0f, w1f, w2f, Wsm, wsmf,
        dist, sw, bo, uTi, species, Wsp, bsm, xi, si16, mi0);

    for (int l = 0; l < LAYERS; ++l) {
        unsigned short* mi_rd = (l & 1) ? mi1 : mi0;
        unsigned short* mi_wr = (l & 1) ? mi0 : mi1;
        k_layer<<<N_NODES / 16, 256, 0, stream>>>(rowptr, edst, uTi, mi_rd, mi_wr,
                                                  si16, w0f, b0, w1f, b1, w2f, b2,
                                                  wsmf, bsm, xi, l);
    }
}

// Round 20
// 91.941 us; speedup vs baseline: 10.7111x; 1.0107x over previous
//
#include <hip/hip_runtime.h>
#include <math.h>

#define N_NODES 20000
#define N_EDGES 320000
#define NCHUNK (N_EDGES / 32)      // 10000
#define CH_STRIDE 1536             // 48 p-rows * 32 edges (ush) per chunk
#define DIM 64
#define SUB 16
#define NRBF 8
#define NB 5
#define LAYERS 3
#define FCIN (NRBF*SUB*NB + SUB)   // 656
#define KPAD 672
#define NKK 21
#define HD 64
#define CUTOFF 5.0f
#define TS 680                     // LDS cat-tile row stride (ush): 2-way banks

// k_setup block-range sizes
#define B_ROWPTR 79                // ceil(20001/256)
#define B_PACKW  600               // (129024 + 24576) / 256
#define B_PACKSM 24                // 6144 / 256
#define B_U      1250              // N_EDGES / 256
#define B_INIT   2500              // N_NODES / 8

typedef __attribute__((ext_vector_type(8))) short short8;
typedef __attribute__((ext_vector_type(4))) float float4v;
typedef __attribute__((ext_vector_type(4))) unsigned short ushort4v;

__device__ __forceinline__ float ssp(float x) {
    float sp = fmaxf(x, 0.0f) + log1pf(expf(-fabsf(x)));
    return sp - 0.69314718055994530942f;
}

__device__ __forceinline__ unsigned short f2bf(float x) {
    unsigned int u = __float_as_uint(x);
    unsigned int r = (u + 0x7FFFu + ((u >> 16) & 1u)) >> 16;
    return (unsigned short)r;
}

// cat' column layout (chosen so Phase A NODE_STORE is contiguous b64 per lane):
//   t in {0,1}: pos = t*256 + s*16 + g*4 + i   (p = t*16 + g*4 + i, s = x)
//   t = 2     : pos = 512 + s*8 + g*4 + i      (p = 32 + g*4 + i, g < 2)
//   si        : pos = 640 + s ; pad 656..671 = 0
// Inverse (pos -> original w0 row) used in w0f packing below.

// --- single setup kernel: rowptr | packw | pack Wsm | uTi | init ------------
__global__ __launch_bounds__(256) void k_setup(
    const int* __restrict__ esrc, int* __restrict__ rowptr,
    const float* __restrict__ w0, const float* __restrict__ w1,
    const float* __restrict__ w2,
    short* __restrict__ w0f, short* __restrict__ w1f, short* __restrict__ w2f,
    const float* __restrict__ Wsm, short* __restrict__ wsmf,
    const float* __restrict__ dist, const float* __restrict__ sw,
    const float* __restrict__ bo, unsigned short* __restrict__ uTi,
    const int* __restrict__ species, const float* __restrict__ Wsp,
    const float* __restrict__ bsm, float* __restrict__ xi,
    unsigned short* __restrict__ si16, unsigned short* __restrict__ mi16)
{
    __shared__ float xs[8][64];
    const unsigned bid = blockIdx.x;

    if (bid < B_ROWPTR) {                       // ---- rowptr ----
        int n = bid * 256 + threadIdx.x;
        if (n > N_NODES) return;
        int a = 0, b = N_EDGES;
        while (a < b) { int m = (a + b) >> 1; if (esrc[m] < n) a = m + 1; else b = m; }
        rowptr[n] = a;
        return;
    }
    if (bid < B_ROWPTR + B_PACKW) {             // ---- pack w0/w1/w2 ----
        const int SZ0 = LAYERS * NKK * 4 * 64 * 8;
        const int SZ12 = LAYERS * 2 * 4 * 64 * 8;
        int i = (bid - B_ROWPTR) * 256 + threadIdx.x;
        if (i < SZ0) {
            int j = i & 7, t = i >> 3;
            int lane = t & 63; t >>= 6;
            int nf = t & 3; t >>= 2;
            int kk = t % NKK, l = t / NKK;
            int kp = kk * 32 + (lane >> 4) * 8 + j;   // pos in new cat' layout
            int col = nf * 16 + (lane & 15);
            float v = 0.0f;
            int orig = -1;
            if (kp < 512) {
                int p = ((kp >> 8) << 4) + (kp & 15);
                int s = (kp >> 4) & 15;
                orig = (p / 5) * 80 + s * 5 + (p % 5);
            } else if (kp < 640) {
                int rem = kp - 512;
                int p = 32 + (rem & 7);
                int s = rem >> 3;
                orig = (p / 5) * 80 + s * 5 + (p % 5);
            } else if (kp < 656) {
                orig = kp;                        // si block
            }
            if (orig >= 0) v = w0[((size_t)l * FCIN + orig) * HD + col];
            w0f[i] = (short)f2bf(v);
            return;
        }
        i -= SZ0;
        if (i < 2 * SZ12) {
            const float* W = (i < SZ12) ? w1 : w2;
            short* Wf = (i < SZ12) ? w1f : w2f;
            int ii = (i < SZ12) ? i : i - SZ12;
            int j = ii & 7, t = ii >> 3;
            int lane = t & 63; t >>= 6;
            int nf = t & 3; t >>= 2;
            int kk = t & 1, l = t >> 1;
            int kp = kk * 32 + (lane >> 4) * 8 + j;
            int col = nf * 16 + (lane & 15);
            Wf[ii] = (short)f2bf(W[((size_t)l * HD + kp) * HD + col]);
        }
        return;
    }
    if (bid < B_ROWPTR + B_PACKW + B_PACKSM) {  // ---- pack Wsm for h-GEMM ----
        int i = (bid - B_ROWPTR - B_PACKW) * 256 + threadIdx.x;   // < 6144
        int j = i & 7, t = i >> 3;
        int lane = t & 63; t >>= 6;
        int nf = t & 1; t >>= 1;
        int kk = t & 1, l = t >> 1;
        int kp = kk * 32 + (lane >> 4) * 8 + j;
        int col = nf * 16 + (lane & 15);
        wsmf[i] = (short)f2bf(Wsm[(size_t)l * DIM * 2 * SUB + kp * 2 * SUB + col]);
        return;
    }
    if (bid < B_ROWPTR + B_PACKW + B_PACKSM + B_U) {   // ---- uTi (chunk-tiled) ----
        int e = (bid - B_ROWPTR - B_PACKW - B_PACKSM) * 256 + threadIdx.x;
        float d = dist[e];
        float s = sw[e];
        float rbv[NRBF], bov[NB];
        #pragma unroll
        for (int r = 0; r < NRBF; ++r) {
            float mu = (CUTOFF / (NRBF - 1)) * (float)r;
            float z = (d - mu) * ((float)NRBF / CUTOFF);
            rbv[r] = s * expf(-0.5f * z * z);
        }
        #pragma unroll
        for (int b = 0; b < NB; ++b) bov[b] = bo[e * NB + b];
        unsigned short* out = uTi + (size_t)(e >> 5) * CH_STRIDE + (e & 31);
        #pragma unroll
        for (int p = 0; p < 48; ++p) {
            float v = (p < 40) ? rbv[p / 5] * bov[p % 5] : 0.0f;
            out[p * 32] = f2bf(v);
        }
        return;
    }
    {                                            // ---- init xi + h(0) ----
        int blk = bid - (B_ROWPTR + B_PACKW + B_PACKSM + B_U);
        const int nl = threadIdx.x >> 5, j = threadIdx.x & 31;
        const int n = blk * 8 + nl;
        const int sp = species[n];
        float v0 = Wsp[sp * DIM + j];
        float v1 = Wsp[sp * DIM + 32 + j];
        xi[(size_t)n * DIM + j] = v0;
        xi[(size_t)n * DIM + 32 + j] = v1;
        xs[nl][j] = v0;
        xs[nl][32 + j] = v1;
        __syncthreads();
        float v = bsm[j];
        const float* xr = &xs[nl][0];
        #pragma unroll 8
        for (int d = 0; d < DIM; ++d) v = fmaf(xr[d], Wsm[d * 2 * SUB + j], v);
        if (j < SUB) si16[(size_t)n * SUB + j] = f2bf(v);
        else         mi16[(size_t)n * SUB + (j - SUB)] = f2bf(v);
    }
}

// --- fused per-layer kernel -------------------------------------------------
// Block = 16 nodes, 4 waves.
// Phase A: union-sweep MFMA aggregation; C written to LDS tile via contiguous
//   b64 stores (new cat' layout -> no bank conflicts).
// Phase B: fc0 (A from LDS tile, w0f packed in matching order) -> fc1 -> fc2
//   + residual -> MFMA h-epilogue.
__global__ __launch_bounds__(256) void k_layer(
    const int* __restrict__ rowptr, const int* __restrict__ edst,
    const unsigned short* __restrict__ uTi,
    const unsigned short* __restrict__ mi_rd,
    unsigned short* __restrict__ mi_wr,
    unsigned short* __restrict__ si16,
    const short* __restrict__ w0f, const float* __restrict__ b0,
    const short* __restrict__ w1f, const float* __restrict__ b1,
    const short* __restrict__ w2f, const float* __restrict__ b2,
    const short* __restrict__ wsmf, const float* __restrict__ bsm,
    float* __restrict__ xi, int l)
{
    __shared__ __align__(16) unsigned short tile[16][TS];    // 21760 B total LDS
    unsigned short (*h1)[72] = (unsigned short (*)[72])((char*)tile);          // 2304 B
    unsigned short (*h2)[72] = (unsigned short (*)[72])((char*)tile + 4608);   // 2304 B
    float (*xi_s)[68]        = (float (*)[68])((char*)tile + 9216);            // 4352 B

    const int lane = threadIdx.x & 63;
    const int w = threadIdx.x >> 6;
    const int n0 = blockIdx.x * 16;
    const int x = lane & 15, g = lane >> 4;

    // ---- Phase A: union-sweep MFMA aggregation into LDS tile ----
    const unsigned short* mx = mi_rd + x;
    const int base = n0 + 4 * w;
    int rp[5];
    {
        int4 r4 = *(const int4*)(rowptr + base);   // base % 4 == 0 -> 16B aligned
        rp[0] = r4.x; rp[1] = r4.y; rp[2] = r4.z; rp[3] = r4.w;
        rp[4] = rowptr[base + 4];
    }

    float4v a00={0,0,0,0}, a01={0,0,0,0}, a02={0,0,0,0};
    float4v a10={0,0,0,0}, a11={0,0,0,0}, a12={0,0,0,0};
    float4v a20={0,0,0,0}, a21={0,0,0,0}, a22={0,0,0,0};
    float4v a30={0,0,0,0}, a31={0,0,0,0}, a32={0,0,0,0};

    const int kb = g * 8;
    for (int ba = rp[0] & ~31; ba < rp[4]; ba += 32) {
        // shared loads for this chunk (once per chunk, all 4 nodes)
        int4 i0 = *(const int4*)(edst + ba + kb);
        int4 i1 = *(const int4*)(edst + ba + kb + 4);
        short8 braw;
        braw[0] = (short)mx[(size_t)i0.x * 16];
        braw[1] = (short)mx[(size_t)i0.y * 16];
        braw[2] = (short)mx[(size_t)i0.z * 16];
        braw[3] = (short)mx[(size_t)i0.w * 16];
        braw[4] = (short)mx[(size_t)i1.x * 16];
        braw[5] = (short)mx[(size_t)i1.y * 16];
        braw[6] = (short)mx[(size_t)i1.z * 16];
        braw[7] = (short)mx[(size_t)i1.w * 16];

        // A-frags: contiguous 1KB per p-tile across the wave
        const unsigned short* ap = uTi + (size_t)(ba >> 5) * CH_STRIDE + x * 32 + kb;
        short8 f0 = *(const short8*)(ap);
        short8 f1 = *(const short8*)(ap + 512);
        short8 f2 = *(const short8*)(ap + 1024);

        #define NODE_STEP(ND, A0, A1, A2)                                     \
        if (ba < rp[ND + 1] && ba + 32 > rp[ND]) {                            \
            const int klo = rp[ND] - ba, khi = rp[ND + 1] - ba;               \
            short8 bq;                                                        \
            if (klo <= 0 && khi >= 32) {                                      \
                bq = braw;                                                    \
            } else {                                                          \
                _Pragma("unroll")                                             \
                for (int j = 0; j < 8; ++j)                                   \
                    bq[j] = (kb + j >= klo && kb + j < khi) ? braw[j] : (short)0; \
            }                                                                 \
            A0 = __builtin_amdgcn_mfma_f32_16x16x32_bf16(f0, bq, A0, 0, 0, 0);\
            A1 = __builtin_amdgcn_mfma_f32_16x16x32_bf16(f1, bq, A1, 0, 0, 0);\
            A2 = __builtin_amdgcn_mfma_f32_16x16x32_bf16(f2, bq, A2, 0, 0, 0);\
        }
        NODE_STEP(0, a00, a01, a02)
        NODE_STEP(1, a10, a11, a12)
        NODE_STEP(2, a20, a21, a22)
        NODE_STEP(3, a30, a31, a32)
        #undef NODE_STEP
    }

    // C-writes: new layout -> contiguous b64 per lane, conflict-free.
    #define NODE_STORE(ND, A0, A1, A2)                                        \
    {                                                                         \
        unsigned short* tp = &tile[4 * w + ND][0];                            \
        ushort4v v;                                                           \
        v[0]=f2bf(A0[0]); v[1]=f2bf(A0[1]); v[2]=f2bf(A0[2]); v[3]=f2bf(A0[3]);\
        *(ushort4v*)(tp + x * 16 + g * 4) = v;                                \
        v[0]=f2bf(A1[0]); v[1]=f2bf(A1[1]); v[2]=f2bf(A1[2]); v[3]=f2bf(A1[3]);\
        *(ushort4v*)(tp + 256 + x * 16 + g * 4) = v;                          \
        if (g < 2) {                                                          \
            v[0]=f2bf(A2[0]); v[1]=f2bf(A2[1]); v[2]=f2bf(A2[2]); v[3]=f2bf(A2[3]);\
            *(ushort4v*)(tp + 512 + x * 8 + g * 4) = v;                       \
        }                                                                     \
        if (lane < SUB)      tp[640 + lane] = si16[(size_t)(base + ND) * SUB + lane]; \
        else if (lane < 32)  tp[640 + lane] = 0;                              \
    }
    NODE_STORE(0, a00, a01, a02)
    NODE_STORE(1, a10, a11, a12)
    NODE_STORE(2, a20, a21, a22)
    NODE_STORE(3, a30, a31, a32)
    #undef NODE_STORE
    __syncthreads();

    // ---- Phase B: MFMA MLP (A-frags from LDS tile) ----
    const int r = x;
    const short* Bp = w0f + ((size_t)l * NKK * 256 + w * 64 + lane) * 8;
    float bv = b0[l * HD + w * 16 + r];
    float4v accA = {bv, bv, bv, bv};
    float4v accB = {0.f, 0.f, 0.f, 0.f};
    #pragma unroll 5
    for (int kk = 0; kk < 20; kk += 2) {
        short8 aA = *(const short8*)((const short*)&tile[r][kk * 32 + g * 8]);
        short8 bA = *(const short8*)(Bp + (size_t)kk * 2048);
        accA = __builtin_amdgcn_mfma_f32_16x16x32_bf16(aA, bA, accA, 0, 0, 0);
        short8 aB = *(const short8*)((const short*)&tile[r][(kk + 1) * 32 + g * 8]);
        short8 bB = *(const short8*)(Bp + (size_t)(kk + 1) * 2048);
        accB = __builtin_amdgcn_mfma_f32_16x16x32_bf16(aB, bB, accB, 0, 0, 0);
    }
    {
        short8 a = *(const short8*)((const short*)&tile[r][20 * 32 + g * 8]);
        short8 b = *(const short8*)(Bp + (size_t)20 * 2048);
        accA = __builtin_amdgcn_mfma_f32_16x16x32_bf16(a, b, accA, 0, 0, 0);
    }
    __syncthreads();   // all tile reads done before h1 overlays it
    #pragma unroll
    for (int i = 0; i < 4; ++i)
        h1[g * 4 + i][w * 16 + r] = f2bf(ssp(accA[i] + accB[i]));
    __syncthreads();

    // fc1
    bv = b1[l * HD + w * 16 + r];
    float4v acc1v = {bv, bv, bv, bv};
    #pragma unroll
    for (int kk = 0; kk < 2; ++kk) {
        short8 a = *(const short8*)((const short*)&h1[r][kk * 32 + g * 8]);
        short8 b = *(const short8*)(w1f + ((size_t)(l * 2 + kk) * 256 + w * 64 + lane) * 8);
        acc1v = __builtin_amdgcn_mfma_f32_16x16x32_bf16(a, b, acc1v, 0, 0, 0);
    }
    #pragma unroll
    for (int i = 0; i < 4; ++i)
        h2[g * 4 + i][w * 16 + r] = f2bf(ssp(acc1v[i]));   // h2 disjoint from h1
    __syncthreads();

    // fc2 + residual; stage fresh xi rows for the h epilogue
    bv = b2[l * DIM + w * 16 + r];
    float4v acc2v = {bv, bv, bv, bv};
    #pragma unroll
    for (int kk = 0; kk < 2; ++kk) {
        short8 a = *(const short8*)((const short*)&h2[r][kk * 32 + g * 8]);
        short8 b = *(const short8*)(w2f + ((size_t)(l * 2 + kk) * 256 + w * 64 + lane) * 8);
        acc2v = __builtin_amdgcn_mfma_f32_16x16x32_bf16(a, b, acc2v, 0, 0, 0);
    }
    #pragma unroll
    for (int i = 0; i < 4; ++i) {
        size_t idx = (size_t)(n0 + g * 4 + i) * DIM + w * 16 + r;
        float nv = xi[idx] + acc2v[i];
        xi[idx] = nv;
        xi_s[g * 4 + i][w * 16 + r] = nv;   // xi_s disjoint from h2
    }

    // h(l+1) epilogue via MFMA: h = bf16(xi) @ bf16(Wsm[l+1]) + b (fp32 accum).
    if (l + 1 < LAYERS) {
        __syncthreads();
        if (w < 2) {
            const float* bs = bsm + (l + 1) * 2 * SUB;
            float bv2 = bs[w * 16 + x];
            float4v hacc = {bv2, bv2, bv2, bv2};
            #pragma unroll
            for (int kk = 0; kk < 2; ++kk) {
                short8 af;
                #pragma unroll
                for (int j = 0; j < 8; ++j)
                    af[j] = (short)f2bf(xi_s[x][kk * 32 + g * 8 + j]);
                short8 bf = *(const short8*)(wsmf +
                    ((((size_t)(l + 1) * 2 + kk) * 2 + w) * 64 + lane) * 8);
                hacc = __builtin_amdgcn_mfma_f32_16x16x32_bf16(af, bf, hacc, 0, 0, 0);
            }
            #pragma unroll
            for (int i = 0; i < 4; ++i) {
                int n = n0 + g * 4 + i;
                unsigned short v = f2bf(hacc[i]);
                if (w == 0) si16[(size_t)n * SUB + x] = v;
                else        mi_wr[(size_t)n * SUB + x] = v;
            }
        }
    }
}

extern "C" void kernel_launch(void* const* d_in, const int* in_sizes, int n_in,
                              void* d_out, int out_size, void* d_ws, size_t ws_size,
                              hipStream_t stream) {
    const int*   species = (const int*)  d_in[0];
    const int*   esrc    = (const int*)  d_in[1];
    const int*   edst    = (const int*)  d_in[2];
    const float* dist    = (const float*)d_in[3];
    const float* sw      = (const float*)d_in[4];
    const float* bo      = (const float*)d_in[5];
    const float* Wsp     = (const float*)d_in[6];
    const float* Wsm     = (const float*)d_in[7];
    const float* bsm     = (const float*)d_in[8];
    const float* w0      = (const float*)d_in[9];
    const float* b0      = (const float*)d_in[10];
    const float* w1      = (const float*)d_in[11];
    const float* b1      = (const float*)d_in[12];
    const float* w2      = (const float*)d_in[13];
    const float* b2      = (const float*)d_in[14];

    float* xi = (float*)d_out;   // N x 64 fp32, updated in place

    // ws layout: uTi NCHUNK*1536 ush | mi16 2 x N*16 ush | si16 N*16 ush |
    //            w0f | w1f | w2f | wsmf | rowptr
    unsigned short* uTi   = (unsigned short*)d_ws;
    unsigned short* mi0   = uTi + (size_t)NCHUNK * CH_STRIDE;
    unsigned short* mi1   = mi0 + (size_t)N_NODES * SUB;
    unsigned short* si16  = mi1 + (size_t)N_NODES * SUB;
    short* w0f  = (short*)(si16 + (size_t)N_NODES * SUB);
    short* w1f  = w0f + (size_t)LAYERS * NKK * 2048;
    short* w2f  = w1f + (size_t)LAYERS * 2 * 2048;
    short* wsmf = w2f + (size_t)LAYERS * 2 * 2048;
    int* rowptr = (int*)(wsmf + (size_t)LAYERS * 2 * 2 * 512);

    k_setup<<<B_ROWPTR + B_PACKW + B_PACKSM + B_U + B_INIT, 256, 0, stream>>>(
        esrc, rowptr, w0, w1, w2, w0f, w1f, w2f, Wsm, wsmf,
        dist, sw, bo, uTi, species, Wsp, bsm, xi, si16, mi0);

    for (int l = 0; l < LAYERS; ++l) {
        unsigned short* mi_rd = (l & 1) ? mi1 : mi0;
        unsigned short* mi_wr = (l & 1) ? mi0 : mi1;
        k_layer<<<N_NODES / 16, 256, 0, stream>>>(rowptr, edst, uTi, mi_rd, mi_wr,
                                                  si16, w0f, b0, w1f, b1, w2f, b2,
                                                  wsmf, bsm, xi, l);
    }
}

// Round 21
// 90.422 us; speedup vs baseline: 10.8910x; 1.0168x over previous
//
#include <hip/hip_runtime.h>
#include <math.h>

#define N_NODES 20000
#define N_EDGES 320000
#define NCHUNK (N_EDGES / 32)      // 10000
#define CH_STRIDE 1280             // 40 p-rows * 32 edges (ush) per chunk
#define DIM 64
#define SUB 16
#define NRBF 8
#define NB 5
#define LAYERS 3
#define FCIN (NRBF*SUB*NB + SUB)   // 656
#define KPAD 672
#define NKK 21
#define HD 64
#define CUTOFF 5.0f
#define TS 680                     // LDS cat-tile row stride (ush)

// k_setup block-range sizes
#define B_ROWPTR 79                // ceil(20001/256)
#define B_PACKW  600               // (129024 + 24576) / 256
#define B_PACKSM 24                // 6144 / 256
#define B_U      1250              // N_EDGES / 256
#define B_INIT   2500              // N_NODES / 8

typedef __attribute__((ext_vector_type(8))) short short8;
typedef __attribute__((ext_vector_type(4))) float float4v;
typedef __attribute__((ext_vector_type(4))) unsigned short ushort4v;

__device__ __forceinline__ float ssp(float x) {
    float sp = fmaxf(x, 0.0f) + log1pf(expf(-fabsf(x)));
    return sp - 0.69314718055994530942f;
}

__device__ __forceinline__ unsigned short f2bf(float x) {
    unsigned int u = __float_as_uint(x);
    unsigned int r = (u + 0x7FFFu + ((u >> 16) & 1u)) >> 16;
    return (unsigned short)r;
}

// cat' column layout (Phase A NODE_STORE contiguous b64 per lane):
//   t in {0,1}: pos = t*256 + s*16 + g*4 + i   (p = t*16 + g*4 + i, s = x)
//   t = 2     : pos = 512 + s*8 + g*4 + i      (p = 32 + g*4 + i, g < 2)
//   si        : pos = 640 + s ; pad 656..671 = 0

// --- single setup kernel: rowptr | packw | pack Wsm | uTi | init ------------
__global__ __launch_bounds__(256) void k_setup(
    const int* __restrict__ esrc, int* __restrict__ rowptr,
    const float* __restrict__ w0, const float* __restrict__ w1,
    const float* __restrict__ w2,
    short* __restrict__ w0f, short* __restrict__ w1f, short* __restrict__ w2f,
    const float* __restrict__ Wsm, short* __restrict__ wsmf,
    const float* __restrict__ dist, const float* __restrict__ sw,
    const float* __restrict__ bo, unsigned short* __restrict__ uTi,
    const int* __restrict__ species, const float* __restrict__ Wsp,
    const float* __restrict__ bsm, float* __restrict__ xi,
    unsigned short* __restrict__ si16, unsigned short* __restrict__ mi16)
{
    __shared__ float xs[8][64];
    const unsigned bid = blockIdx.x;

    if (bid < B_ROWPTR) {                       // ---- rowptr ----
        int n = bid * 256 + threadIdx.x;
        if (n > N_NODES) return;
        int a = 0, b = N_EDGES;
        while (a < b) { int m = (a + b) >> 1; if (esrc[m] < n) a = m + 1; else b = m; }
        rowptr[n] = a;
        return;
    }
    if (bid < B_ROWPTR + B_PACKW) {             // ---- pack w0/w1/w2 ----
        const int SZ0 = LAYERS * NKK * 4 * 64 * 8;
        const int SZ12 = LAYERS * 2 * 4 * 64 * 8;
        int i = (bid - B_ROWPTR) * 256 + threadIdx.x;
        if (i < SZ0) {
            int j = i & 7, t = i >> 3;
            int lane = t & 63; t >>= 6;
            int nf = t & 3; t >>= 2;
            int kk = t % NKK, l = t / NKK;
            int kp = kk * 32 + (lane >> 4) * 8 + j;   // pos in cat' layout
            int col = nf * 16 + (lane & 15);
            float v = 0.0f;
            int orig = -1;
            if (kp < 512) {
                int p = ((kp >> 8) << 4) + (kp & 15);
                int s = (kp >> 4) & 15;
                orig = (p / 5) * 80 + s * 5 + (p % 5);
            } else if (kp < 640) {
                int rem = kp - 512;
                int p = 32 + (rem & 7);
                int s = rem >> 3;
                orig = (p / 5) * 80 + s * 5 + (p % 5);
            } else if (kp < 656) {
                orig = kp;                        // si block
            }
            if (orig >= 0) v = w0[((size_t)l * FCIN + orig) * HD + col];
            w0f[i] = (short)f2bf(v);
            return;
        }
        i -= SZ0;
        if (i < 2 * SZ12) {
            const float* W = (i < SZ12) ? w1 : w2;
            short* Wf = (i < SZ12) ? w1f : w2f;
            int ii = (i < SZ12) ? i : i - SZ12;
            int j = ii & 7, t = ii >> 3;
            int lane = t & 63; t >>= 6;
            int nf = t & 3; t >>= 2;
            int kk = t & 1, l = t >> 1;
            int kp = kk * 32 + (lane >> 4) * 8 + j;
            int col = nf * 16 + (lane & 15);
            Wf[ii] = (short)f2bf(W[((size_t)l * HD + kp) * HD + col]);
        }
        return;
    }
    if (bid < B_ROWPTR + B_PACKW + B_PACKSM) {  // ---- pack Wsm for h-GEMM ----
        int i = (bid - B_ROWPTR - B_PACKW) * 256 + threadIdx.x;   // < 6144
        int j = i & 7, t = i >> 3;
        int lane = t & 63; t >>= 6;
        int nf = t & 1; t >>= 1;
        int kk = t & 1, l = t >> 1;
        int kp = kk * 32 + (lane >> 4) * 8 + j;
        int col = nf * 16 + (lane & 15);
        wsmf[i] = (short)f2bf(Wsm[(size_t)l * DIM * 2 * SUB + kp * 2 * SUB + col]);
        return;
    }
    if (bid < B_ROWPTR + B_PACKW + B_PACKSM + B_U) {   // ---- uTi (chunk-tiled, 40 rows) ----
        int e = (bid - B_ROWPTR - B_PACKW - B_PACKSM) * 256 + threadIdx.x;
        float d = dist[e];
        float s = sw[e];
        float rbv[NRBF], bov[NB];
        #pragma unroll
        for (int r = 0; r < NRBF; ++r) {
            float mu = (CUTOFF / (NRBF - 1)) * (float)r;
            float z = (d - mu) * ((float)NRBF / CUTOFF);
            rbv[r] = s * expf(-0.5f * z * z);
        }
        #pragma unroll
        for (int b = 0; b < NB; ++b) bov[b] = bo[e * NB + b];
        unsigned short* out = uTi + (size_t)(e >> 5) * CH_STRIDE + (e & 31);
        #pragma unroll
        for (int p = 0; p < 40; ++p)
            out[p * 32] = f2bf(rbv[p / 5] * bov[p % 5]);
        return;
    }
    {                                            // ---- init xi + h(0) ----
        int blk = bid - (B_ROWPTR + B_PACKW + B_PACKSM + B_U);
        const int nl = threadIdx.x >> 5, j = threadIdx.x & 31;
        const int n = blk * 8 + nl;
        const int sp = species[n];
        float v0 = Wsp[sp * DIM + j];
        float v1 = Wsp[sp * DIM + 32 + j];
        xi[(size_t)n * DIM + j] = v0;
        xi[(size_t)n * DIM + 32 + j] = v1;
        xs[nl][j] = v0;
        xs[nl][32 + j] = v1;
        __syncthreads();
        float v = bsm[j];
        const float* xr = &xs[nl][0];
        #pragma unroll 8
        for (int d = 0; d < DIM; ++d) v = fmaf(xr[d], Wsm[d * 2 * SUB + j], v);
        if (j < SUB) si16[(size_t)n * SUB + j] = f2bf(v);
        else         mi16[(size_t)n * SUB + (j - SUB)] = f2bf(v);
    }
}

// --- fused per-layer kernel -------------------------------------------------
__global__ __launch_bounds__(256) void k_layer(
    const int* __restrict__ rowptr, const int* __restrict__ edst,
    const unsigned short* __restrict__ uTi,
    const unsigned short* __restrict__ mi_rd,
    unsigned short* __restrict__ mi_wr,
    unsigned short* __restrict__ si16,
    const short* __restrict__ w0f, const float* __restrict__ b0,
    const short* __restrict__ w1f, const float* __restrict__ b1,
    const short* __restrict__ w2f, const float* __restrict__ b2,
    const short* __restrict__ wsmf, const float* __restrict__ bsm,
    float* __restrict__ xi, int l)
{
    __shared__ __align__(16) unsigned short tile[16][TS];    // 21760 B total LDS
    unsigned short (*h1)[72] = (unsigned short (*)[72])((char*)tile);          // 2304 B
    unsigned short (*h2)[72] = (unsigned short (*)[72])((char*)tile + 4608);   // 2304 B
    float (*xi_s)[68]        = (float (*)[68])((char*)tile + 9216);            // 4352 B

    const int lane = threadIdx.x & 63;
    const int w = threadIdx.x >> 6;
    const int n0 = blockIdx.x * 16;
    const int x = lane & 15, g = lane >> 4;

    // ---- Phase A: union-sweep MFMA aggregation into LDS tile ----
    const unsigned short* mx = mi_rd + x;
    const int base = n0 + 4 * w;
    int rp[5];
    {
        int4 r4 = *(const int4*)(rowptr + base);
        rp[0] = r4.x; rp[1] = r4.y; rp[2] = r4.z; rp[3] = r4.w;
        rp[4] = rowptr[base + 4];
    }

    float4v a00={0,0,0,0}, a01={0,0,0,0}, a02={0,0,0,0};
    float4v a10={0,0,0,0}, a11={0,0,0,0}, a12={0,0,0,0};
    float4v a20={0,0,0,0}, a21={0,0,0,0}, a22={0,0,0,0};
    float4v a30={0,0,0,0}, a31={0,0,0,0}, a32={0,0,0,0};

    const int kb = g * 8;
    #pragma unroll 2
    for (int ba = rp[0] & ~31; ba < rp[4]; ba += 32) {
        // shared loads for this chunk (once per chunk, all 4 nodes)
        int4 i0 = *(const int4*)(edst + ba + kb);
        int4 i1 = *(const int4*)(edst + ba + kb + 4);
        short8 braw;
        braw[0] = (short)mx[(unsigned)(i0.x * 16)];
        braw[1] = (short)mx[(unsigned)(i0.y * 16)];
        braw[2] = (short)mx[(unsigned)(i0.z * 16)];
        braw[3] = (short)mx[(unsigned)(i0.w * 16)];
        braw[4] = (short)mx[(unsigned)(i1.x * 16)];
        braw[5] = (short)mx[(unsigned)(i1.y * 16)];
        braw[6] = (short)mx[(unsigned)(i1.z * 16)];
        braw[7] = (short)mx[(unsigned)(i1.w * 16)];

        // A-frags: contiguous per p-tile; tile 2 has only 8 real rows (x<8)
        const unsigned short* ap = uTi + (size_t)(ba >> 5) * CH_STRIDE + x * 32 + kb;
        short8 f0 = *(const short8*)(ap);
        short8 f1 = *(const short8*)(ap + 512);
        short8 f2 = {0, 0, 0, 0, 0, 0, 0, 0};
        if (x < 8) f2 = *(const short8*)(ap + 1024);

        #define NODE_STEP(ND, A0, A1, A2)                                     \
        if (ba < rp[ND + 1] && ba + 32 > rp[ND]) {                            \
            const int klo = rp[ND] - ba, khi = rp[ND + 1] - ba;               \
            short8 bq;                                                        \
            if (klo <= 0 && khi >= 32) {                                      \
                bq = braw;                                                    \
            } else {                                                          \
                _Pragma("unroll")                                             \
                for (int j = 0; j < 8; ++j)                                   \
                    bq[j] = (kb + j >= klo && kb + j < khi) ? braw[j] : (short)0; \
            }                                                                 \
            A0 = __builtin_amdgcn_mfma_f32_16x16x32_bf16(f0, bq, A0, 0, 0, 0);\
            A1 = __builtin_amdgcn_mfma_f32_16x16x32_bf16(f1, bq, A1, 0, 0, 0);\
            A2 = __builtin_amdgcn_mfma_f32_16x16x32_bf16(f2, bq, A2, 0, 0, 0);\
        }
        NODE_STEP(0, a00, a01, a02)
        NODE_STEP(1, a10, a11, a12)
        NODE_STEP(2, a20, a21, a22)
        NODE_STEP(3, a30, a31, a32)
        #undef NODE_STEP
    }

    // C-writes: contiguous b64 per lane, conflict-free.
    #define NODE_STORE(ND, A0, A1, A2)                                        \
    {                                                                         \
        unsigned short* tp = &tile[4 * w + ND][0];                            \
        ushort4v v;                                                           \
        v[0]=f2bf(A0[0]); v[1]=f2bf(A0[1]); v[2]=f2bf(A0[2]); v[3]=f2bf(A0[3]);\
        *(ushort4v*)(tp + x * 16 + g * 4) = v;                                \
        v[0]=f2bf(A1[0]); v[1]=f2bf(A1[1]); v[2]=f2bf(A1[2]); v[3]=f2bf(A1[3]);\
        *(ushort4v*)(tp + 256 + x * 16 + g * 4) = v;                          \
        if (g < 2) {                                                          \
            v[0]=f2bf(A2[0]); v[1]=f2bf(A2[1]); v[2]=f2bf(A2[2]); v[3]=f2bf(A2[3]);\
            *(ushort4v*)(tp + 512 + x * 8 + g * 4) = v;                       \
        }                                                                     \
        if (lane < SUB)      tp[640 + lane] = si16[(size_t)(base + ND) * SUB + lane]; \
        else if (lane < 32)  tp[640 + lane] = 0;                              \
    }
    NODE_STORE(0, a00, a01, a02)
    NODE_STORE(1, a10, a11, a12)
    NODE_STORE(2, a20, a21, a22)
    NODE_STORE(3, a30, a31, a32)
    #undef NODE_STORE
    __syncthreads();

    // ---- Phase B: MFMA MLP (A-frags from LDS tile) ----
    const int r = x;
    const short* Bp = w0f + ((size_t)l * NKK * 256 + w * 64 + lane) * 8;
    float bv = b0[l * HD + w * 16 + r];
    float4v accA = {bv, bv, bv, bv};
    float4v accB = {0.f, 0.f, 0.f, 0.f};
    #pragma unroll 5
    for (int kk = 0; kk < 20; kk += 2) {
        short8 aA = *(const short8*)((const short*)&tile[r][kk * 32 + g * 8]);
        short8 bA = *(const short8*)(Bp + (size_t)kk * 2048);
        accA = __builtin_amdgcn_mfma_f32_16x16x32_bf16(aA, bA, accA, 0, 0, 0);
        short8 aB = *(const short8*)((const short*)&tile[r][(kk + 1) * 32 + g * 8]);
        short8 bB = *(const short8*)(Bp + (size_t)(kk + 1) * 2048);
        accB = __builtin_amdgcn_mfma_f32_16x16x32_bf16(aB, bB, accB, 0, 0, 0);
    }
    {
        short8 a = *(const short8*)((const short*)&tile[r][20 * 32 + g * 8]);
        short8 b = *(const short8*)(Bp + (size_t)20 * 2048);
        accA = __builtin_amdgcn_mfma_f32_16x16x32_bf16(a, b, accA, 0, 0, 0);
    }
    __syncthreads();   // all tile reads done before h1 overlays it
    #pragma unroll
    for (int i = 0; i < 4; ++i)
        h1[g * 4 + i][w * 16 + r] = f2bf(ssp(accA[i] + accB[i]));
    __syncthreads();

    // fc1
    bv = b1[l * HD + w * 16 + r];
    float4v acc1v = {bv, bv, bv, bv};
    #pragma unroll
    for (int kk = 0; kk < 2; ++kk) {
        short8 a = *(const short8*)((const short*)&h1[r][kk * 32 + g * 8]);
        short8 b = *(const short8*)(w1f + ((size_t)(l * 2 + kk) * 256 + w * 64 + lane) * 8);
        acc1v = __builtin_amdgcn_mfma_f32_16x16x32_bf16(a, b, acc1v, 0, 0, 0);
    }
    #pragma unroll
    for (int i = 0; i < 4; ++i)
        h2[g * 4 + i][w * 16 + r] = f2bf(ssp(acc1v[i]));
    __syncthreads();

    // fc2 + residual; stage fresh xi rows for the h epilogue
    bv = b2[l * DIM + w * 16 + r];
    float4v acc2v = {bv, bv, bv, bv};
    #pragma unroll
    for (int kk = 0; kk < 2; ++kk) {
        short8 a = *(const short8*)((const short*)&h2[r][kk * 32 + g * 8]);
        short8 b = *(const short8*)(w2f + ((size_t)(l * 2 + kk) * 256 + w * 64 + lane) * 8);
        acc2v = __builtin_amdgcn_mfma_f32_16x16x32_bf16(a, b, acc2v, 0, 0, 0);
    }
    #pragma unroll
    for (int i = 0; i < 4; ++i) {
        size_t idx = (size_t)(n0 + g * 4 + i) * DIM + w * 16 + r;
        float nv = xi[idx] + acc2v[i];
        xi[idx] = nv;
        xi_s[g * 4 + i][w * 16 + r] = nv;
    }

    // h(l+1) epilogue via MFMA
    if (l + 1 < LAYERS) {
        __syncthreads();
        if (w < 2) {
            const float* bs = bsm + (l + 1) * 2 * SUB;
            float bv2 = bs[w * 16 + x];
            float4v hacc = {bv2, bv2, bv2, bv2};
            #pragma unroll
            for (int kk = 0; kk < 2; ++kk) {
                short8 af;
                #pragma unroll
                for (int j = 0; j < 8; ++j)
                    af[j] = (short)f2bf(xi_s[x][kk * 32 + g * 8 + j]);
                short8 bf = *(const short8*)(wsmf +
                    ((((size_t)(l + 1) * 2 + kk) * 2 + w) * 64 + lane) * 8);
                hacc = __builtin_amdgcn_mfma_f32_16x16x32_bf16(af, bf, hacc, 0, 0, 0);
            }
            #pragma unroll
            for (int i = 0; i < 4; ++i) {
                int n = n0 + g * 4 + i;
                unsigned short v = f2bf(hacc[i]);
                if (w == 0) si16[(size_t)n * SUB + x] = v;
                else        mi_wr[(size_t)n * SUB + x] = v;
            }
        }
    }
}

extern "C" void kernel_launch(void* const* d_in, const int* in_sizes, int n_in,
                              void* d_out, int out_size, void* d_ws, size_t ws_size,
                              hipStream_t stream) {
    const int*   species = (const int*)  d_in[0];
    const int*   esrc    = (const int*)  d_in[1];
    const int*   edst    = (const int*)  d_in[2];
    const float* dist    = (const float*)d_in[3];
    const float* sw      = (const float*)d_in[4];
    const float* bo      = (const float*)d_in[5];
    const float* Wsp     = (const float*)d_in[6];
    const float* Wsm     = (const float*)d_in[7];
    const float* bsm     = (const float*)d_in[8];
    const float* w0      = (const float*)d_in[9];
    const float* b0      = (const float*)d_in[10];
    const float* w1      = (const float*)d_in[11];
    const float* b1      = (const float*)d_in[12];
    const float* w2      = (const float*)d_in[13];
    const float* b2      = (const float*)d_in[14];

    float* xi = (float*)d_out;   // N x 64 fp32, updated in place

    // ws layout: uTi NCHUNK*1280 ush | mi16 2 x N*16 ush | si16 N*16 ush |
    //            w0f | w1f | w2f | wsmf | rowptr
    unsigned short* uTi   = (unsigned short*)d_ws;
    unsigned short* mi0   = uTi + (size_t)NCHUNK * CH_STRIDE;
    unsigned short* mi1   = mi0 + (size_t)N_NODES * SUB;
    unsigned short* si16  = mi1 + (size_t)N_NODES * SUB;
    short* w0f  = (short*)(si16 + (size_t)N_NODES * SUB);
    short* w1f  = w0f + (size_t)LAYERS * NKK * 2048;
    short* w2f  = w1f + (size_t)LAYERS * 2 * 2048;
    short* wsmf = w2f + (size_t)LAYERS * 2 * 2048;
    int* rowptr = (int*)(wsmf + (size_t)LAYERS * 2 * 2 * 512);

    k_setup<<<B_ROWPTR + B_PACKW + B_PACKSM + B_U + B_INIT, 256, 0, stream>>>(
        esrc, rowptr, w0, w1, w2, w0f, w1f, w2f, Wsm, wsmf,
        dist, sw, bo, uTi, species, Wsp, bsm, xi, si16, mi0);

    for (int l = 0; l < LAYERS; ++l) {
        unsigned short* mi_rd = (l & 1) ? mi1 : mi0;
        unsigned short* mi_wr = (l & 1) ? mi0 : mi1;
        k_layer<<<N_NODES / 16, 256, 0, stream>>>(rowptr, edst, uTi, mi_rd, mi_wr,
                                                  si16, w0f, b0, w1f, b1, w2f, b2,
                                                  wsmf, bsm, xi, l);
    }
}